// Round 2
// baseline (814.594 us; speedup 1.0000x reference)
//
#include <hip/hip_runtime.h>
#include <stdint.h>

typedef unsigned int u32;
typedef unsigned short u16;
typedef __attribute__((ext_vector_type(8))) short bf16x8;
typedef __attribute__((ext_vector_type(16))) float f32x16;

#define DEVI __device__ __forceinline__

// ---------------- numeric helpers ----------------
DEVI u16 f2b_rne(float f) {
  u32 u = __float_as_uint(f);
  u += 0x7FFFu + ((u >> 16) & 1u);
  return (u16)(u >> 16);
}
// pack high 16 bits of two f32 bit-patterns: [bf16(hi)][bf16(lo)] (truncate)
DEVI u32 pack_hi16(u32 hi, u32 lo) {
  return __builtin_amdgcn_perm(hi, lo, 0x07060302u);
}
DEVI u32 mul2bf(u32 a, u32 b) {  // two bf16 lanes: product, repacked bf16
  float a0 = __uint_as_float(a << 16);
  float a1 = __uint_as_float(a & 0xFFFF0000u);
  float b0 = __uint_as_float(b << 16);
  float b1 = __uint_as_float(b & 0xFFFF0000u);
  return pack_hi16(__float_as_uint(a1 * b1), __float_as_uint(a0 * b0));
}
DEVI u32 absdiff2bf(u32 a, u32 b) {  // two bf16 lanes: |a-b|, repacked bf16
  float a0 = __uint_as_float(a << 16);
  float a1 = __uint_as_float(a & 0xFFFF0000u);
  float b0 = __uint_as_float(b << 16);
  float b1 = __uint_as_float(b & 0xFFFF0000u);
  return pack_hi16(__float_as_uint(fabsf(a1 - b1)), __float_as_uint(fabsf(a0 - b0)));
}

// ---------------- ws layout (bytes) ----------------
#define WS_E16 0
#define WS_WT (1u << 20)
#define WS_A (3u << 20)
#define WS_C (5u << 20)

// ---------------- kernel 0a: E -> bf16 ----------------
__global__ void k_cvt_e(const float* __restrict__ E, u16* __restrict__ E16) {
  int i = (blockIdx.x * blockDim.x + threadIdx.x) * 4;  // 524288 total, exact
  float4 v = *(const float4*)(E + i);
  ushort4 o;
  o.x = f2b_rne(v.x); o.y = f2b_rne(v.y); o.z = f2b_rne(v.z); o.w = f2b_rne(v.w);
  *(ushort4*)(E16 + i) = o;
}

// ---------------- kernel 0b: W1 (2048x512 f32) -> W16T (512x2048 bf16) ----------------
__global__ void k_cvt_w(const float* __restrict__ W1, u16* __restrict__ WT) {
  __shared__ float tile[64][65];
  int t = threadIdx.x;
  int kBase = blockIdx.x * 64;   // 32 tiles
  int chBase = blockIdx.y * 64;  // 8 tiles
  int lr = t >> 4, lc = (t & 15) * 4;
  for (int rr = 0; rr < 4; rr++) {
    int kr = lr + rr * 16;
    float4 v = *(const float4*)(W1 + (kBase + kr) * 512 + chBase + lc);
    tile[kr][lc] = v.x; tile[kr][lc + 1] = v.y;
    tile[kr][lc + 2] = v.z; tile[kr][lc + 3] = v.w;
  }
  __syncthreads();
  int ch = t >> 2, ks = (t & 3) * 16;
  u32 w[8];
  for (int u = 0; u < 8; u++) {
    u16 lo = f2b_rne(tile[ks + 2 * u][ch]);
    u16 hi = f2b_rne(tile[ks + 2 * u + 1][ch]);
    w[u] = (u32)lo | ((u32)hi << 16);
  }
  u16* dst = WT + (chBase + ch) * 2048 + kBase + ks;
  uint4 s0; s0.x = w[0]; s0.y = w[1]; s0.z = w[2]; s0.w = w[3];
  uint4 s1; s1.x = w[4]; s1.y = w[5]; s1.z = w[6]; s1.w = w[7];
  *(uint4*)(dst) = s0;
  *(uint4*)(dst + 8) = s1;
}

// ---------------- kernel 1: a = E@Wa, c = E@Wb (bf16 MFMA, f32 out) ----------------
// M=1024 rows, N'=1024 (a||c), K=512. 128x128 block tile, 4 waves 2x2, wave 64x64.
__global__ __launch_bounds__(256, 4) void k_ac(const u16* __restrict__ E16,
                                               const u16* __restrict__ WT,
                                               float* __restrict__ Aw,
                                               float* __restrict__ Cw) {
  __shared__ __align__(16) char smem[16384];
  char* sA = smem;         // [128 rows][32 k] bf16, 16B-group xor swizzle
  char* sB = smem + 8192;  // [128 ch][32 k] bf16
  const int tid = threadIdx.x;
  const int lane = tid & 63, wid = tid >> 6;
  const int wr = wid >> 1, wcl = wid & 1;
  const int n = lane & 31, q = lane >> 5;
  const int rowBase = blockIdx.y * 128;
  const int chBase = blockIdx.x * 128;
  const int halfOff = (chBase >= 512) ? 512 : 0;  // a-half vs c-half of W1
  const int chSrc0 = chBase - halfOff;
  f32x16 acc[2][2];
  for (int a = 0; a < 2; a++)
    for (int c = 0; c < 2; c++)
      for (int e = 0; e < 16; e++) acc[a][c][e] = 0.f;
  for (int kc = 0; kc < 16; kc++) {
    const int k0 = kc * 32;
    __syncthreads();
    for (int s2 = 0; s2 < 2; s2++) {
      int s = tid * 2 + s2;
      // swizzle: phys 16B-group = pg ^ ((row>>1)&3)  (row stride 64B = 16 banks,
      // rows alias with period 2 -> must fold row bit1..2, not bit0..1)
      int row = s >> 2, pg = s & 3, lg = pg ^ ((row >> 1) & 3);
      *(uint4*)(sA + row * 64 + lg * 16) =
          *(const uint4*)(E16 + (rowBase + row) * 512 + k0 + pg * 8);
      *(uint4*)(sB + row * 64 + lg * 16) =
          *(const uint4*)(WT + (chSrc0 + row) * 2048 + halfOff + k0 + pg * 8);
    }
    __syncthreads();
    for (int ks = 0; ks < 2; ks++) {
      int kg = ks * 2 + q;
      bf16x8 af[2], bfr[2];
      for (int rb = 0; rb < 2; rb++) {
        int row = wr * 64 + rb * 32 + n;
        af[rb] = *(const bf16x8*)(sA + row * 64 + ((kg ^ ((row >> 1) & 3)) * 16));
      }
      for (int cb = 0; cb < 2; cb++) {
        int ch = wcl * 64 + cb * 32 + n;
        bfr[cb] = *(const bf16x8*)(sB + ch * 64 + ((kg ^ ((ch >> 1) & 3)) * 16));
      }
      for (int rb = 0; rb < 2; rb++)
        for (int cb = 0; cb < 2; cb++)
          acc[rb][cb] = __builtin_amdgcn_mfma_f32_32x32x16_bf16(af[rb], bfr[cb],
                                                               acc[rb][cb], 0, 0, 0);
    }
  }
  for (int rb = 0; rb < 2; rb++)
    for (int cb = 0; cb < 2; cb++)
      for (int r = 0; r < 16; r++) {
        int rowl = (r & 3) + 8 * (r >> 2) + 4 * q;  // C/D layout (m74/m101)
        int rowg = rowBase + wr * 64 + rb * 32 + rowl;
        int chg = chBase + wcl * 64 + cb * 32 + n;
        float v = acc[rb][cb][r];
        if (chg < 512) Aw[rowg * 512 + chg] = v;
        else Cw[rowg * 512 + chg - 512] = v;
      }
}

// ---------------- kernel 2: pair kernel ----------------
// Block: 8 i x 16 j = 128 pairs, 256 thr (4 waves, 2x2), 2 channel passes of 256,
// K=1024 ([u;v] vs W1 rows 1024..2047) in chunks of 32. Wave tile 64 pairs x 128 ch.
#define ESTR 520  // e-row stride in LDS (elems): breaks bank alignment, keeps 16B align
#define EI_OFF 0             // 8*520*2   = 8320
#define EJ_OFF 8320          // 16*520*2  = 16640 -> 24960
#define A2_OFF 24960         // 128*32*2  = 8192  -> 33152
#define B2_OFF 33152         // 256*32*2  = 16384 -> 49536
#define CJB_OFF 24960        // epilogue alias: 16*256*4 = 16384
#define W2S_OFF 41344        // 256*4 = 1024
#define RED_OFF 49536        // [128][9] f32 = 4608
#define SMEM2 54144

// 54272 B rounded LDS x 3 = 162816 <= 163840: 3 blocks/CU fit; VGPR 128 <= 170.
__global__ __launch_bounds__(256, 3) void k_pair(
    const u16* __restrict__ E16, const u16* __restrict__ WT,
    const float* __restrict__ Aw, const float* __restrict__ Cw,
    const float* __restrict__ b1, const float* __restrict__ w2,
    const float* __restrict__ b2, float* __restrict__ out) {
  __shared__ __align__(16) char smem[SMEM2];
  const int tid = threadIdx.x;
  const int lane = tid & 63, wid = tid >> 6;
  const int wr = wid >> 1, wcl = wid & 1;
  const int n = lane & 31, q = lane >> 5;
  const int bb = blockIdx.z;
  const int bi0 = blockIdx.y * 8;
  const int bj0 = blockIdx.x * 16;

  // stage e-tiles into LDS (rows 0..7 = e_i tile, 8..23 = e_j tile)
  for (int s = tid; s < 1536; s += 256) {
    int row = s >> 6, c16 = s & 63;
    int grow = (row < 8) ? (bi0 + row) : (bj0 + row - 8);
    const u16* src = E16 + (bb * 256 + grow) * 512 + c16 * 8;
    int off = (row < 8) ? (EI_OFF + (row * ESTR + c16 * 8) * 2)
                        : (EJ_OFF + ((row - 8) * ESTR + c16 * 8) * 2);
    *(uint4*)(smem + off) = *(const uint4*)src;
  }

  float* RED = (float*)(smem + RED_OFF);

  for (int pass = 0; pass < 2; pass++) {
    const int ch0 = pass * 256;
    f32x16 acc[2][4];
    for (int a = 0; a < 2; a++)
      for (int c = 0; c < 4; c++)
        for (int e = 0; e < 16; e++) acc[a][c][e] = 0.f;

    for (int kc = 0; kc < 32; kc++) {
      const int k0 = kc * 32;
      const int dB = k0 & 511;       // source d within e-rows
      const bool isV = (k0 >= 512);  // u-part (e_i*e_j) vs v-part |e_i-e_j|
      __syncthreads();
      // stage B chunk [256 ch][32 k] bf16 from W16T rows, cols 1024+k0..
      for (int s2 = 0; s2 < 4; s2++) {
        int s = tid + 256 * s2;
        int row = s >> 2, pg = s & 3, lg = pg ^ ((row >> 1) & 3);
        *(uint4*)(smem + B2_OFF + row * 64 + lg * 16) =
            *(const uint4*)(WT + (ch0 + row) * 2048 + 1024 + k0 + pg * 8);
      }
      // form A chunk [128 pairs][32 k]
      {
        int p = tid >> 1;
        int iL = p >> 4, jL = p & 15;
        const char* ei = smem + EI_OFF + iL * (ESTR * 2);
        const char* ej = smem + EJ_OFF + jL * (ESTR * 2);
        for (int s2 = 0; s2 < 2; s2++) {
          int kg = 2 * (tid & 1) + s2;
          int d0 = dB + kg * 8;
          uint4 va = *(const uint4*)(ei + d0 * 2);
          uint4 vb = *(const uint4*)(ej + d0 * 2);
          uint4 o;
          if (!isV) {
            o.x = mul2bf(va.x, vb.x); o.y = mul2bf(va.y, vb.y);
            o.z = mul2bf(va.z, vb.z); o.w = mul2bf(va.w, vb.w);
          } else {
            o.x = absdiff2bf(va.x, vb.x); o.y = absdiff2bf(va.y, vb.y);
            o.z = absdiff2bf(va.z, vb.z); o.w = absdiff2bf(va.w, vb.w);
          }
          *(uint4*)(smem + A2_OFF + p * 64 + ((kg ^ ((p >> 1) & 3)) * 16)) = o;
        }
      }
      __syncthreads();
      // MFMA: 2 ksteps x (2 row-blocks x 4 ch-blocks)
      for (int ks = 0; ks < 2; ks++) {
        int kg = ks * 2 + q;
        bf16x8 af[2], bfr[4];
        for (int rb = 0; rb < 2; rb++) {
          int row = wr * 64 + rb * 32 + n;
          af[rb] = *(const bf16x8*)(smem + A2_OFF + row * 64 +
                                    ((kg ^ ((row >> 1) & 3)) * 16));
        }
        for (int cb = 0; cb < 4; cb++) {
          int ch = wcl * 128 + cb * 32 + n;
          bfr[cb] = *(const bf16x8*)(smem + B2_OFF + ch * 64 +
                                     ((kg ^ ((ch >> 1) & 3)) * 16));
        }
        for (int rb = 0; rb < 2; rb++)
          for (int cb = 0; cb < 4; cb++)
            acc[rb][cb] = __builtin_amdgcn_mfma_f32_32x32x16_bf16(af[rb], bfr[cb],
                                                                 acc[rb][cb], 0, 0, 0);
      }
    }

    // ---- epilogue for this pass ----
    __syncthreads();
    {
      float b1v = b1[ch0 + tid];
      for (int j = 0; j < 16; j++)
        *(float*)(smem + CJB_OFF + (j * 256 + tid) * 4) =
            Cw[(bb * 256 + bj0 + j) * 512 + ch0 + tid] + b1v;
      *(float*)(smem + W2S_OFF + tid * 4) = w2[ch0 + tid];
    }
    __syncthreads();

    const float* CJB = (const float*)(smem + CJB_OFF);
    const float* W2S = (const float*)(smem + W2S_OFF);
    for (int rb = 0; rb < 2; rb++) {
      float av[4][2], w2v[4];
      int chls[4];
      for (int cb = 0; cb < 4; cb++) {
        int chl = wcl * 128 + cb * 32 + n;
        chls[cb] = chl;
        w2v[cb] = W2S[chl];
        int irow = bb * 256 + bi0 + wr * 4 + rb * 2;
        av[cb][0] = Aw[irow * 512 + ch0 + chl];
        av[cb][1] = Aw[(irow + 1) * 512 + ch0 + chl];
      }
      for (int r = 0; r < 16; r++) {
        int rowl = (r & 3) + 8 * (r >> 2) + 4 * q;  // C/D layout
        int j = rowl & 15;
        int hi = r >> 3;
        float v = 0.f;
        for (int cb = 0; cb < 4; cb++) {
          float h = acc[rb][cb][r] + av[cb][hi] + CJB[j * 256 + chls[cb]];
          if (h > 0.f) v += h * w2v[cb];
        }
        v += __shfl_xor(v, 1);
        v += __shfl_xor(v, 2);
        v += __shfl_xor(v, 4);
        if ((n & 7) == 0) {
          int p = wr * 64 + rb * 32 + rowl;
          int slot = p * 9 + wcl * 4 + (n >> 3);
          if (pass == 0) RED[slot] = v;
          else RED[slot] += v;
        }
      }
    }
  }

  __syncthreads();
  if (tid < 128) {
    float s = b2[0];
    for (int u = 0; u < 8; u++) s += RED[tid * 9 + u];
    out[(bb * 256 + bi0 + (tid >> 4)) * 256 + bj0 + (tid & 15)] = s;
  }
}

// ---------------- launcher ----------------
extern "C" void kernel_launch(void* const* d_in, const int* in_sizes, int n_in,
                              void* d_out, int out_size, void* d_ws, size_t ws_size,
                              hipStream_t stream) {
  const float* E = (const float*)d_in[0];
  const float* W1 = (const float*)d_in[1];
  const float* b1 = (const float*)d_in[2];
  const float* W2 = (const float*)d_in[3];
  const float* b2 = (const float*)d_in[4];
  float* out = (float*)d_out;
  char* ws = (char*)d_ws;
  u16* E16 = (u16*)(ws + WS_E16);
  u16* WT = (u16*)(ws + WS_WT);
  float* Aw = (float*)(ws + WS_A);
  float* Cw = (float*)(ws + WS_C);

  hipLaunchKernelGGL(k_cvt_e, dim3(512), dim3(256), 0, stream, E, E16);
  hipLaunchKernelGGL(k_cvt_w, dim3(32, 8), dim3(256), 0, stream, W1, WT);
  hipLaunchKernelGGL(k_ac, dim3(8, 8), dim3(256), 0, stream, E16, WT, Aw, Cw);
  hipLaunchKernelGGL(k_pair, dim3(16, 32, 4), dim3(256), 0, stream,
                     E16, WT, Aw, Cw, b1, W2, b2, out);
}

// Round 3
// 462.508 us; speedup vs baseline: 1.7613x; 1.7613x over previous
//
#include <hip/hip_runtime.h>
#include <stdint.h>

typedef unsigned int u32;
typedef unsigned short u16;
typedef __attribute__((ext_vector_type(8))) short bf16x8;
typedef __attribute__((ext_vector_type(16))) float f32x16;

#define DEVI __device__ __forceinline__

// ---------------- numeric helpers ----------------
DEVI u16 f2b_rne(float f) {
  u32 u = __float_as_uint(f);
  u += 0x7FFFu + ((u >> 16) & 1u);
  return (u16)(u >> 16);
}
// pack high 16 bits of two f32 bit-patterns: [bf16(hi)][bf16(lo)] (truncate)
DEVI u32 pack_hi16(u32 hi, u32 lo) {
  return __builtin_amdgcn_perm(hi, lo, 0x07060302u);
}
DEVI u32 mul2bf(u32 a, u32 b) {  // two bf16 lanes: product, repacked bf16
  float a0 = __uint_as_float(a << 16);
  float a1 = __uint_as_float(a & 0xFFFF0000u);
  float b0 = __uint_as_float(b << 16);
  float b1 = __uint_as_float(b & 0xFFFF0000u);
  return pack_hi16(__float_as_uint(a1 * b1), __float_as_uint(a0 * b0));
}
DEVI u32 absdiff2bf(u32 a, u32 b) {  // two bf16 lanes: |a-b|, repacked bf16
  float a0 = __uint_as_float(a << 16);
  float a1 = __uint_as_float(a & 0xFFFF0000u);
  float b0 = __uint_as_float(b << 16);
  float b1 = __uint_as_float(b & 0xFFFF0000u);
  return pack_hi16(__float_as_uint(fabsf(a1 - b1)), __float_as_uint(fabsf(a0 - b0)));
}

// ---------------- ws layout (bytes) ----------------
#define WS_E16 0
#define WS_WT (1u << 20)
#define WS_A (3u << 20)
#define WS_C (5u << 20)

// ---------------- kernel 0a: E -> bf16 ----------------
__global__ void k_cvt_e(const float* __restrict__ E, u16* __restrict__ E16) {
  int i = (blockIdx.x * blockDim.x + threadIdx.x) * 4;  // 524288 total, exact
  float4 v = *(const float4*)(E + i);
  ushort4 o;
  o.x = f2b_rne(v.x); o.y = f2b_rne(v.y); o.z = f2b_rne(v.z); o.w = f2b_rne(v.w);
  *(ushort4*)(E16 + i) = o;
}

// ---------------- kernel 0b: W1 (2048x512 f32) -> W16T (512x2048 bf16) ----------------
__global__ void k_cvt_w(const float* __restrict__ W1, u16* __restrict__ WT) {
  __shared__ float tile[64][65];
  int t = threadIdx.x;
  int kBase = blockIdx.x * 64;   // 32 tiles
  int chBase = blockIdx.y * 64;  // 8 tiles
  int lr = t >> 4, lc = (t & 15) * 4;
  for (int rr = 0; rr < 4; rr++) {
    int kr = lr + rr * 16;
    float4 v = *(const float4*)(W1 + (kBase + kr) * 512 + chBase + lc);
    tile[kr][lc] = v.x; tile[kr][lc + 1] = v.y;
    tile[kr][lc + 2] = v.z; tile[kr][lc + 3] = v.w;
  }
  __syncthreads();
  int ch = t >> 2, ks = (t & 3) * 16;
  u32 w[8];
  for (int u = 0; u < 8; u++) {
    u16 lo = f2b_rne(tile[ks + 2 * u][ch]);
    u16 hi = f2b_rne(tile[ks + 2 * u + 1][ch]);
    w[u] = (u32)lo | ((u32)hi << 16);
  }
  u16* dst = WT + (chBase + ch) * 2048 + kBase + ks;
  uint4 s0; s0.x = w[0]; s0.y = w[1]; s0.z = w[2]; s0.w = w[3];
  uint4 s1; s1.x = w[4]; s1.y = w[5]; s1.z = w[6]; s1.w = w[7];
  *(uint4*)(dst) = s0;
  *(uint4*)(dst + 8) = s1;
}

// ---------------- kernel 1: a = E@Wa, c = E@Wb (bf16 MFMA, f32 out) ----------------
// M=1024 rows, N'=1024 (a||c), K=512. 128x128 block tile, 4 waves 2x2, wave 64x64.
__global__ __launch_bounds__(256, 4) void k_ac(const u16* __restrict__ E16,
                                               const u16* __restrict__ WT,
                                               float* __restrict__ Aw,
                                               float* __restrict__ Cw) {
  __shared__ __align__(16) char smem[16384];
  char* sA = smem;         // [128 rows][32 k] bf16, 16B-group xor swizzle
  char* sB = smem + 8192;  // [128 ch][32 k] bf16
  const int tid = threadIdx.x;
  const int lane = tid & 63, wid = tid >> 6;
  const int wr = wid >> 1, wcl = wid & 1;
  const int n = lane & 31, q = lane >> 5;
  const int rowBase = blockIdx.y * 128;
  const int chBase = blockIdx.x * 128;
  const int halfOff = (chBase >= 512) ? 512 : 0;  // a-half vs c-half of W1
  const int chSrc0 = chBase - halfOff;
  f32x16 acc[2][2];
  for (int a = 0; a < 2; a++)
    for (int c = 0; c < 2; c++)
      for (int e = 0; e < 16; e++) acc[a][c][e] = 0.f;
  for (int kc = 0; kc < 16; kc++) {
    const int k0 = kc * 32;
    __syncthreads();
    for (int s2 = 0; s2 < 2; s2++) {
      int s = tid * 2 + s2;
      // swizzle: phys 16B-group = pg ^ ((row>>1)&3)  (row stride 64B = 16 banks,
      // rows alias with period 2 -> fold row bits 1..2)
      int row = s >> 2, pg = s & 3, lg = pg ^ ((row >> 1) & 3);
      *(uint4*)(sA + row * 64 + lg * 16) =
          *(const uint4*)(E16 + (rowBase + row) * 512 + k0 + pg * 8);
      *(uint4*)(sB + row * 64 + lg * 16) =
          *(const uint4*)(WT + (chSrc0 + row) * 2048 + halfOff + k0 + pg * 8);
    }
    __syncthreads();
    for (int ks = 0; ks < 2; ks++) {
      int kg = ks * 2 + q;
      bf16x8 af[2], bfr[2];
      for (int rb = 0; rb < 2; rb++) {
        int row = wr * 64 + rb * 32 + n;
        af[rb] = *(const bf16x8*)(sA + row * 64 + ((kg ^ ((row >> 1) & 3)) * 16));
      }
      for (int cb = 0; cb < 2; cb++) {
        int ch = wcl * 64 + cb * 32 + n;
        bfr[cb] = *(const bf16x8*)(sB + ch * 64 + ((kg ^ ((ch >> 1) & 3)) * 16));
      }
      for (int rb = 0; rb < 2; rb++)
        for (int cb = 0; cb < 2; cb++)
          acc[rb][cb] = __builtin_amdgcn_mfma_f32_32x32x16_bf16(af[rb], bfr[cb],
                                                               acc[rb][cb], 0, 0, 0);
    }
  }
  for (int rb = 0; rb < 2; rb++)
    for (int cb = 0; cb < 2; cb++)
      for (int r = 0; r < 16; r++) {
        int rowl = (r & 3) + 8 * (r >> 2) + 4 * q;  // C/D layout (m74/m101)
        int rowg = rowBase + wr * 64 + rb * 32 + rowl;
        int chg = chBase + wcl * 64 + cb * 32 + n;
        float v = acc[rb][cb][r];
        if (chg < 512) Aw[rowg * 512 + chg] = v;
        else Cw[rowg * 512 + chg - 512] = v;
      }
}

// ---------------- kernel 2: pair kernel ----------------
// Block: 8 i x 16 j = 128 pairs, 256 thr (4 waves, 2x2), 2 channel passes of 256,
// K=1024 ([u;v] vs W1 rows 1024..2047) in chunks of 32. Wave tile 64 pairs x 128 ch.
#define ESTR 520  // e-row stride in LDS (elems): breaks bank alignment, keeps 16B align
#define EI_OFF 0             // 8*520*2   = 8320
#define EJ_OFF 8320          // 16*520*2  = 16640 -> 24960
#define A2_OFF 24960         // 128*32*2  = 8192  -> 33152
#define B2_OFF 33152         // 256*32*2  = 16384 -> 49536
#define CJB_OFF 24960        // epilogue alias: 16*256*4 = 16384
#define W2S_OFF 41344        // 256*4 = 1024
#define RED_OFF 49536        // [128][9] f32 = 4608
#define SMEM2 54144

// Occupancy note: acc[2][4] = 128 AGPRs + ~80 arch VGPRs on the unified gfx950
// RF -> ~210 total. launch_bounds(256,3) caps at ~170 and SPILLS the
// accumulators to scratch (R2: 163 MB scratch writes, dur 777us). 2 blocks/CU
// is the structural max for this wave tile.
__global__ __launch_bounds__(256, 2) void k_pair(
    const u16* __restrict__ E16, const u16* __restrict__ WT,
    const float* __restrict__ Aw, const float* __restrict__ Cw,
    const float* __restrict__ b1, const float* __restrict__ w2,
    const float* __restrict__ b2, float* __restrict__ out) {
  __shared__ __align__(16) char smem[SMEM2];
  const int tid = threadIdx.x;
  const int lane = tid & 63, wid = tid >> 6;
  const int wr = wid >> 1, wcl = wid & 1;
  const int n = lane & 31, q = lane >> 5;
  const int bb = blockIdx.z;
  const int bi0 = blockIdx.y * 8;
  const int bj0 = blockIdx.x * 16;

  // stage e-tiles into LDS (rows 0..7 = e_i tile, 8..23 = e_j tile)
  for (int s = tid; s < 1536; s += 256) {
    int row = s >> 6, c16 = s & 63;
    int grow = (row < 8) ? (bi0 + row) : (bj0 + row - 8);
    const u16* src = E16 + (bb * 256 + grow) * 512 + c16 * 8;
    int off = (row < 8) ? (EI_OFF + (row * ESTR + c16 * 8) * 2)
                        : (EJ_OFF + ((row - 8) * ESTR + c16 * 8) * 2);
    *(uint4*)(smem + off) = *(const uint4*)src;
  }

  float* RED = (float*)(smem + RED_OFF);

  for (int pass = 0; pass < 2; pass++) {
    const int ch0 = pass * 256;
    f32x16 acc[2][4];
    for (int a = 0; a < 2; a++)
      for (int c = 0; c < 4; c++)
        for (int e = 0; e < 16; e++) acc[a][c][e] = 0.f;

    for (int kc = 0; kc < 32; kc++) {
      const int k0 = kc * 32;
      const int dB = k0 & 511;       // source d within e-rows
      const bool isV = (k0 >= 512);  // u-part (e_i*e_j) vs v-part |e_i-e_j|
      __syncthreads();
      // stage B chunk [256 ch][32 k] bf16 from W16T rows, cols 1024+k0..
      for (int s2 = 0; s2 < 4; s2++) {
        int s = tid + 256 * s2;
        int row = s >> 2, pg = s & 3, lg = pg ^ ((row >> 1) & 3);
        *(uint4*)(smem + B2_OFF + row * 64 + lg * 16) =
            *(const uint4*)(WT + (ch0 + row) * 2048 + 1024 + k0 + pg * 8);
      }
      // form A chunk [128 pairs][32 k]
      {
        int p = tid >> 1;
        int iL = p >> 4, jL = p & 15;
        const char* ei = smem + EI_OFF + iL * (ESTR * 2);
        const char* ej = smem + EJ_OFF + jL * (ESTR * 2);
        for (int s2 = 0; s2 < 2; s2++) {
          int kg = 2 * (tid & 1) + s2;
          int d0 = dB + kg * 8;
          uint4 va = *(const uint4*)(ei + d0 * 2);
          uint4 vb = *(const uint4*)(ej + d0 * 2);
          uint4 o;
          if (!isV) {
            o.x = mul2bf(va.x, vb.x); o.y = mul2bf(va.y, vb.y);
            o.z = mul2bf(va.z, vb.z); o.w = mul2bf(va.w, vb.w);
          } else {
            o.x = absdiff2bf(va.x, vb.x); o.y = absdiff2bf(va.y, vb.y);
            o.z = absdiff2bf(va.z, vb.z); o.w = absdiff2bf(va.w, vb.w);
          }
          *(uint4*)(smem + A2_OFF + p * 64 + ((kg ^ ((p >> 1) & 3)) * 16)) = o;
        }
      }
      __syncthreads();
      // MFMA: 2 ksteps x (2 row-blocks x 4 ch-blocks)
      for (int ks = 0; ks < 2; ks++) {
        int kg = ks * 2 + q;
        bf16x8 af[2], bfr[4];
        for (int rb = 0; rb < 2; rb++) {
          int row = wr * 64 + rb * 32 + n;
          af[rb] = *(const bf16x8*)(smem + A2_OFF + row * 64 +
                                    ((kg ^ ((row >> 1) & 3)) * 16));
        }
        for (int cb = 0; cb < 4; cb++) {
          int ch = wcl * 128 + cb * 32 + n;
          bfr[cb] = *(const bf16x8*)(smem + B2_OFF + ch * 64 +
                                     ((kg ^ ((ch >> 1) & 3)) * 16));
        }
        for (int rb = 0; rb < 2; rb++)
          for (int cb = 0; cb < 4; cb++)
            acc[rb][cb] = __builtin_amdgcn_mfma_f32_32x32x16_bf16(af[rb], bfr[cb],
                                                                 acc[rb][cb], 0, 0, 0);
      }
    }

    // ---- epilogue for this pass ----
    __syncthreads();
    {
      float b1v = b1[ch0 + tid];
      for (int j = 0; j < 16; j++)
        *(float*)(smem + CJB_OFF + (j * 256 + tid) * 4) =
            Cw[(bb * 256 + bj0 + j) * 512 + ch0 + tid] + b1v;
      *(float*)(smem + W2S_OFF + tid * 4) = w2[ch0 + tid];
    }
    __syncthreads();

    const float* CJB = (const float*)(smem + CJB_OFF);
    const float* W2S = (const float*)(smem + W2S_OFF);
    for (int rb = 0; rb < 2; rb++) {
      float av[4][2], w2v[4];
      int chls[4];
      for (int cb = 0; cb < 4; cb++) {
        int chl = wcl * 128 + cb * 32 + n;
        chls[cb] = chl;
        w2v[cb] = W2S[chl];
        int irow = bb * 256 + bi0 + wr * 4 + rb * 2;
        av[cb][0] = Aw[irow * 512 + ch0 + chl];
        av[cb][1] = Aw[(irow + 1) * 512 + ch0 + chl];
      }
      for (int r = 0; r < 16; r++) {
        int rowl = (r & 3) + 8 * (r >> 2) + 4 * q;  // C/D layout
        int j = rowl & 15;
        int hi = r >> 3;
        float v = 0.f;
        for (int cb = 0; cb < 4; cb++) {
          float h = acc[rb][cb][r] + av[cb][hi] + CJB[j * 256 + chls[cb]];
          if (h > 0.f) v += h * w2v[cb];
        }
        v += __shfl_xor(v, 1);
        v += __shfl_xor(v, 2);
        v += __shfl_xor(v, 4);
        if ((n & 7) == 0) {
          int p = wr * 64 + rb * 32 + rowl;
          int slot = p * 9 + wcl * 4 + (n >> 3);
          if (pass == 0) RED[slot] = v;
          else RED[slot] += v;
        }
      }
    }
  }

  __syncthreads();
  if (tid < 128) {
    float s = b2[0];
    for (int u = 0; u < 8; u++) s += RED[tid * 9 + u];
    out[(bb * 256 + bi0 + (tid >> 4)) * 256 + bj0 + (tid & 15)] = s;
  }
}

// ---------------- launcher ----------------
extern "C" void kernel_launch(void* const* d_in, const int* in_sizes, int n_in,
                              void* d_out, int out_size, void* d_ws, size_t ws_size,
                              hipStream_t stream) {
  const float* E = (const float*)d_in[0];
  const float* W1 = (const float*)d_in[1];
  const float* b1 = (const float*)d_in[2];
  const float* W2 = (const float*)d_in[3];
  const float* b2 = (const float*)d_in[4];
  float* out = (float*)d_out;
  char* ws = (char*)d_ws;
  u16* E16 = (u16*)(ws + WS_E16);
  u16* WT = (u16*)(ws + WS_WT);
  float* Aw = (float*)(ws + WS_A);
  float* Cw = (float*)(ws + WS_C);

  hipLaunchKernelGGL(k_cvt_e, dim3(512), dim3(256), 0, stream, E, E16);
  hipLaunchKernelGGL(k_cvt_w, dim3(32, 8), dim3(256), 0, stream, W1, WT);
  hipLaunchKernelGGL(k_ac, dim3(8, 8), dim3(256), 0, stream, E16, WT, Aw, Cw);
  hipLaunchKernelGGL(k_pair, dim3(16, 32, 4), dim3(256), 0, stream,
                     E16, WT, Aw, Cw, b1, W2, b2, out);
}

// Round 4
// 458.682 us; speedup vs baseline: 1.7759x; 1.0083x over previous
//
#include <hip/hip_runtime.h>
#include <stdint.h>

typedef unsigned int u32;
typedef unsigned short u16;
typedef __attribute__((ext_vector_type(8))) short bf16x8;
typedef __attribute__((ext_vector_type(16))) float f32x16;

#define DEVI __device__ __forceinline__

// ---------------- numeric helpers ----------------
DEVI u16 f2b_rne(float f) {
  u32 u = __float_as_uint(f);
  u += 0x7FFFu + ((u >> 16) & 1u);
  return (u16)(u >> 16);
}
DEVI u32 pack_hi16(u32 hi, u32 lo) {
  return __builtin_amdgcn_perm(hi, lo, 0x07060302u);
}
DEVI u32 mul2bf(u32 a, u32 b) {
  float a0 = __uint_as_float(a << 16);
  float a1 = __uint_as_float(a & 0xFFFF0000u);
  float b0 = __uint_as_float(b << 16);
  float b1 = __uint_as_float(b & 0xFFFF0000u);
  return pack_hi16(__float_as_uint(a1 * b1), __float_as_uint(a0 * b0));
}
DEVI u32 absdiff2bf(u32 a, u32 b) {
  float a0 = __uint_as_float(a << 16);
  float a1 = __uint_as_float(a & 0xFFFF0000u);
  float b0 = __uint_as_float(b << 16);
  float b1 = __uint_as_float(b & 0xFFFF0000u);
  return pack_hi16(__float_as_uint(fabsf(a1 - b1)), __float_as_uint(fabsf(a0 - b0)));
}
DEVI uint4 form_u4(uint4 a, uint4 b) {
  uint4 o;
  o.x = mul2bf(a.x, b.x); o.y = mul2bf(a.y, b.y);
  o.z = mul2bf(a.z, b.z); o.w = mul2bf(a.w, b.w);
  return o;
}
DEVI uint4 form_v4(uint4 a, uint4 b) {
  uint4 o;
  o.x = absdiff2bf(a.x, b.x); o.y = absdiff2bf(a.y, b.y);
  o.z = absdiff2bf(a.z, b.z); o.w = absdiff2bf(a.w, b.w);
  return o;
}

// ---------------- ws layout (bytes) ----------------
#define WS_E16 0
#define WS_WT (1u << 20)
#define WS_A (3u << 20)
#define WS_C (5u << 20)

// ---------------- kernel 0a: E -> bf16 ----------------
__global__ void k_cvt_e(const float* __restrict__ E, u16* __restrict__ E16) {
  int i = (blockIdx.x * blockDim.x + threadIdx.x) * 4;
  float4 v = *(const float4*)(E + i);
  ushort4 o;
  o.x = f2b_rne(v.x); o.y = f2b_rne(v.y); o.z = f2b_rne(v.z); o.w = f2b_rne(v.w);
  *(ushort4*)(E16 + i) = o;
}

// ---------------- kernel 0b: W1 (2048x512 f32) -> W16T (512x2048 bf16) ----------------
__global__ void k_cvt_w(const float* __restrict__ W1, u16* __restrict__ WT) {
  __shared__ float tile[64][65];
  int t = threadIdx.x;
  int kBase = blockIdx.x * 64;
  int chBase = blockIdx.y * 64;
  int lr = t >> 4, lc = (t & 15) * 4;
  for (int rr = 0; rr < 4; rr++) {
    int kr = lr + rr * 16;
    float4 v = *(const float4*)(W1 + (kBase + kr) * 512 + chBase + lc);
    tile[kr][lc] = v.x; tile[kr][lc + 1] = v.y;
    tile[kr][lc + 2] = v.z; tile[kr][lc + 3] = v.w;
  }
  __syncthreads();
  int ch = t >> 2, ks = (t & 3) * 16;
  u32 w[8];
  for (int u = 0; u < 8; u++) {
    u16 lo = f2b_rne(tile[ks + 2 * u][ch]);
    u16 hi = f2b_rne(tile[ks + 2 * u + 1][ch]);
    w[u] = (u32)lo | ((u32)hi << 16);
  }
  u16* dst = WT + (chBase + ch) * 2048 + kBase + ks;
  uint4 s0; s0.x = w[0]; s0.y = w[1]; s0.z = w[2]; s0.w = w[3];
  uint4 s1; s1.x = w[4]; s1.y = w[5]; s1.z = w[6]; s1.w = w[7];
  *(uint4*)(dst) = s0;
  *(uint4*)(dst + 8) = s1;
}

// ---------------- kernel 1: a = E@Wa, c = E@Wb ----------------
__global__ __launch_bounds__(256, 4) void k_ac(const u16* __restrict__ E16,
                                               const u16* __restrict__ WT,
                                               float* __restrict__ Aw,
                                               float* __restrict__ Cw) {
  __shared__ __align__(16) char smem[16384];
  char* sA = smem;
  char* sB = smem + 8192;
  const int tid = threadIdx.x;
  const int lane = tid & 63, wid = tid >> 6;
  const int wr = wid >> 1, wcl = wid & 1;
  const int n = lane & 31, q = lane >> 5;
  const int rowBase = blockIdx.y * 128;
  const int chBase = blockIdx.x * 128;
  const int halfOff = (chBase >= 512) ? 512 : 0;
  const int chSrc0 = chBase - halfOff;
  f32x16 acc[2][2];
  for (int a = 0; a < 2; a++)
    for (int c = 0; c < 2; c++)
      for (int e = 0; e < 16; e++) acc[a][c][e] = 0.f;
  for (int kc = 0; kc < 16; kc++) {
    const int k0 = kc * 32;
    __syncthreads();
    for (int s2 = 0; s2 < 2; s2++) {
      int s = tid * 2 + s2;
      int row = s >> 2, pg = s & 3, lg = pg ^ ((row >> 1) & 3);
      *(uint4*)(sA + row * 64 + lg * 16) =
          *(const uint4*)(E16 + (rowBase + row) * 512 + k0 + pg * 8);
      *(uint4*)(sB + row * 64 + lg * 16) =
          *(const uint4*)(WT + (chSrc0 + row) * 2048 + halfOff + k0 + pg * 8);
    }
    __syncthreads();
    for (int ks = 0; ks < 2; ks++) {
      int kg = ks * 2 + q;
      bf16x8 af[2], bfr[2];
      for (int rb = 0; rb < 2; rb++) {
        int row = wr * 64 + rb * 32 + n;
        af[rb] = *(const bf16x8*)(sA + row * 64 + ((kg ^ ((row >> 1) & 3)) * 16));
      }
      for (int cb = 0; cb < 2; cb++) {
        int ch = wcl * 64 + cb * 32 + n;
        bfr[cb] = *(const bf16x8*)(sB + ch * 64 + ((kg ^ ((ch >> 1) & 3)) * 16));
      }
      for (int rb = 0; rb < 2; rb++)
        for (int cb = 0; cb < 2; cb++)
          acc[rb][cb] = __builtin_amdgcn_mfma_f32_32x32x16_bf16(af[rb], bfr[cb],
                                                               acc[rb][cb], 0, 0, 0);
    }
  }
  for (int rb = 0; rb < 2; rb++)
    for (int cb = 0; cb < 2; cb++)
      for (int r = 0; r < 16; r++) {
        int rowl = (r & 3) + 8 * (r >> 2) + 4 * q;
        int rowg = rowBase + wr * 64 + rb * 32 + rowl;
        int chg = chBase + wcl * 64 + cb * 32 + n;
        float v = acc[rb][cb][r];
        if (chg < 512) Aw[rowg * 512 + chg] = v;
        else Cw[rowg * 512 + chg - 512] = v;
      }
}

// ---------------- kernel 2: pair kernel (restructured K-loop) ----------------
// Block: 8 i x 16 j = 128 pairs, 256 thr (2x2 waves), 2 ch passes of 256,
// K=1024 in chunks of 32. A-fragments formed IN-REGISTER from LDS e-tiles
// (no A LDS round-trip). B double-buffered via async global_load_lds; ONE
// raw s_barrier per kc with vmcnt(0)-only drain (prefetch overlaps compute).
#define ESTR 520             // e-row stride elems (1040B): row bank-shift 4, 16B-aligned
#define EI_OFF 0             // 8*1040  = 8320
#define EJ_OFF 8320          // 16*1040 = 16640 -> 24960
#define BB_OFF 24960         // 2 x 16384 -> 57728
#define CJB_OFF 41344        // epilogue alias over Bbuf1 (16*256*4 = 16384)
#define W2S_OFF 57728        // 1024 -> 58752
#define RED_OFF 58752        // 128*9*4 = 4608 -> 63360
#define SMEM2 63360

// acc[2][4]=128 AGPR + ~124 VGPR: 2 waves/SIMD is the structural max (R2 spill lesson).
__global__ __launch_bounds__(256, 2) void k_pair(
    const u16* __restrict__ E16, const u16* __restrict__ WT,
    const float* __restrict__ Aw, const float* __restrict__ Cw,
    const float* __restrict__ b1, const float* __restrict__ w2,
    const float* __restrict__ b2, float* __restrict__ out) {
  __shared__ __align__(16) char smem[SMEM2];
  const int tid = threadIdx.x;
  const int lane = tid & 63, wid = tid >> 6;
  const int wr = wid >> 1, wcl = wid & 1;
  const int n = lane & 31, q = lane >> 5;
  const int bb = blockIdx.z;
  const int bi0 = blockIdx.y * 8;
  const int bj0 = blockIdx.x * 16;

  // async-stage one B tile [256 ch][32 k] into buffer nbuf; gather addresses
  // chosen so lane-linear LDS order reproduces the xor-swizzled layout.
  auto prefetch_B = [&](int npass, int nkc, int nbuf) {
    const int nch0 = npass * 256, nk0 = nkc * 32;
    char* base = smem + BB_OFF + nbuf * 16384 + wid * 4096;
    for (int t = 0; t < 4; t++) {
      int seg = wid * 4 + t;
      int row = seg * 16 + (lane >> 2);
      int pg = (lane & 3) ^ ((row >> 1) & 3);
      const u16* g = WT + (nch0 + row) * 2048 + 1024 + nk0 + pg * 8;
      __builtin_amdgcn_global_load_lds(
          (const __attribute__((address_space(1))) void*)g,
          (__attribute__((address_space(3))) void*)(base + t * 1024), 16, 0, 0);
    }
  };

  // issue first B prefetch immediately; latency overlaps e-tile staging
  prefetch_B(0, 0, 0);

  // stage e-tiles (rows 0..7 = e_i, 8..23 = e_j)
  for (int s = tid; s < 1536; s += 256) {
    int row = s >> 6, c16 = s & 63;
    int grow = (row < 8) ? (bi0 + row) : (bj0 + row - 8);
    const u16* src = E16 + (bb * 256 + grow) * 512 + c16 * 8;
    int off = (row < 8) ? (EI_OFF + (row * ESTR + c16 * 8) * 2)
                        : (EJ_OFF + ((row - 8) * ESTR + c16 * 8) * 2);
    *(uint4*)(smem + off) = *(const uint4*)src;
  }
  __syncthreads();  // e-tiles visible; also drains first prefetch (fine)

  float* RED = (float*)(smem + RED_OFF);

  for (int pass = 0; pass < 2; pass++) {
    const int ch0 = pass * 256;
    f32x16 acc[2][4];
    for (int a = 0; a < 2; a++)
      for (int c = 0; c < 4; c++)
        for (int e = 0; e < 16; e++) acc[a][c][e] = 0.f;

    for (int kc = 0; kc < 32; kc++) {
      const int buf = kc & 1;
      // B(kc) complete (own stores) + all waves' stores visible
      asm volatile("s_waitcnt vmcnt(0)\n\ts_barrier" ::: "memory");
      // prefetch next tile into the other buffer; overlaps this kc's compute
      int lcn = pass * 32 + kc + 1;
      if (lcn < 64) prefetch_B(lcn >> 5, lcn & 31, buf ^ 1);

      const int dBase = (kc * 32) & 511;
      const bool isV = kc >= 16;
      const char* B2 = smem + BB_OFF + buf * 16384;
      for (int ks = 0; ks < 2; ks++) {
        const int d0 = dBase + ks * 16 + q * 8;
        bf16x8 af[2];
        for (int rb = 0; rb < 2; rb++) {
          int p = wr * 64 + rb * 32 + n;  // pair row in block
          uint4 va = *(const uint4*)(smem + EI_OFF + ((p >> 4) * ESTR + d0) * 2);
          uint4 vb = *(const uint4*)(smem + EJ_OFF + ((p & 15) * ESTR + d0) * 2);
          uint4 o = isV ? form_v4(va, vb) : form_u4(va, vb);
          af[rb] = __builtin_bit_cast(bf16x8, o);
        }
        const int kg = ks * 2 + q;
        bf16x8 bfr[4];
        for (int cb = 0; cb < 4; cb++) {
          int ch = wcl * 128 + cb * 32 + n;
          bfr[cb] = *(const bf16x8*)(B2 + ch * 64 + ((kg ^ ((ch >> 1) & 3)) * 16));
        }
        for (int rb = 0; rb < 2; rb++)
          for (int cb = 0; cb < 4; cb++)
            acc[rb][cb] = __builtin_amdgcn_mfma_f32_32x32x16_bf16(af[rb], bfr[cb],
                                                                 acc[rb][cb], 0, 0, 0);
      }
    }

    // ---- epilogue for this pass ----
    __syncthreads();  // all waves done with Bbuf1 (kc=31) before CJB overwrite
    {
      float b1v = b1[ch0 + tid];
      for (int j = 0; j < 16; j++)
        *(float*)(smem + CJB_OFF + (j * 256 + tid) * 4) =
            Cw[(bb * 256 + bj0 + j) * 512 + ch0 + tid] + b1v;
      *(float*)(smem + W2S_OFF + tid * 4) = w2[ch0 + tid];
    }
    __syncthreads();

    const float* CJB = (const float*)(smem + CJB_OFF);
    const float* W2S = (const float*)(smem + W2S_OFF);
    for (int rb = 0; rb < 2; rb++) {
      float av[4][2], w2v[4];
      int chls[4];
      for (int cb = 0; cb < 4; cb++) {
        int chl = wcl * 128 + cb * 32 + n;
        chls[cb] = chl;
        w2v[cb] = W2S[chl];
        int irow = bb * 256 + bi0 + wr * 4 + rb * 2;
        av[cb][0] = Aw[irow * 512 + ch0 + chl];
        av[cb][1] = Aw[(irow + 1) * 512 + ch0 + chl];
      }
      for (int r = 0; r < 16; r++) {
        int rowl = (r & 3) + 8 * (r >> 2) + 4 * q;  // C/D layout (m74/m101)
        int j = rowl & 15;
        int hi = r >> 3;
        float v = 0.f;
        for (int cb = 0; cb < 4; cb++) {
          float h = acc[rb][cb][r] + av[cb][hi] + CJB[j * 256 + chls[cb]];
          if (h > 0.f) v += h * w2v[cb];
        }
        v += __shfl_xor(v, 1);
        v += __shfl_xor(v, 2);
        v += __shfl_xor(v, 4);
        if ((n & 7) == 0) {
          int p = wr * 64 + rb * 32 + rowl;
          int slot = p * 9 + wcl * 4 + (n >> 3);
          if (pass == 0) RED[slot] = v;
          else RED[slot] += v;
        }
      }
    }
  }

  __syncthreads();
  if (tid < 128) {
    float s = b2[0];
    for (int u = 0; u < 8; u++) s += RED[tid * 9 + u];
    out[(bb * 256 + bi0 + (tid >> 4)) * 256 + bj0 + (tid & 15)] = s;
  }
}

// ---------------- launcher ----------------
extern "C" void kernel_launch(void* const* d_in, const int* in_sizes, int n_in,
                              void* d_out, int out_size, void* d_ws, size_t ws_size,
                              hipStream_t stream) {
  const float* E = (const float*)d_in[0];
  const float* W1 = (const float*)d_in[1];
  const float* b1 = (const float*)d_in[2];
  const float* W2 = (const float*)d_in[3];
  const float* b2 = (const float*)d_in[4];
  float* out = (float*)d_out;
  char* ws = (char*)d_ws;
  u16* E16 = (u16*)(ws + WS_E16);
  u16* WT = (u16*)(ws + WS_WT);
  float* Aw = (float*)(ws + WS_A);
  float* Cw = (float*)(ws + WS_C);

  hipLaunchKernelGGL(k_cvt_e, dim3(512), dim3(256), 0, stream, E, E16);
  hipLaunchKernelGGL(k_cvt_w, dim3(32, 8), dim3(256), 0, stream, W1, WT);
  hipLaunchKernelGGL(k_ac, dim3(8, 8), dim3(256), 0, stream, E16, WT, Aw, Cw);
  hipLaunchKernelGGL(k_pair, dim3(16, 32, 4), dim3(256), 0, stream,
                     E16, WT, Aw, Cw, b1, W2, b2, out);
}

// Round 5
// 442.076 us; speedup vs baseline: 1.8427x; 1.0376x over previous
//
#include <hip/hip_runtime.h>
#include <stdint.h>

typedef unsigned int u32;
typedef unsigned short u16;
typedef __attribute__((ext_vector_type(8))) short bf16x8;
typedef __attribute__((ext_vector_type(16))) float f32x16;
typedef __attribute__((ext_vector_type(2))) float f32x2;

#define DEVI __device__ __forceinline__

// ---------------- numeric helpers ----------------
DEVI u16 f2b_rne(float f) {
  u32 u = __float_as_uint(f);
  u += 0x7FFFu + ((u >> 16) & 1u);
  return (u16)(u >> 16);
}
// pack truncated bf16 of two f32: [bf16(v.y)][bf16(v.x)]
DEVI u32 packpair(f32x2 v) {
  return __builtin_amdgcn_perm(__float_as_uint(v.y), __float_as_uint(v.x),
                               0x07060302u);
}
DEVI float bflo(u32 w) { return __uint_as_float(w << 16); }
DEVI float bfhi(u32 w) { return __uint_as_float(w & 0xFFFF0000u); }

// ---------------- ws layout (bytes) ----------------
#define WS_E16 0
#define WS_WT (1u << 20)
#define WS_A (3u << 20)
#define WS_C (5u << 20)

// ---------------- kernel 0a: E -> bf16 ----------------
__global__ void k_cvt_e(const float* __restrict__ E, u16* __restrict__ E16) {
  int i = (blockIdx.x * blockDim.x + threadIdx.x) * 4;
  float4 v = *(const float4*)(E + i);
  ushort4 o;
  o.x = f2b_rne(v.x); o.y = f2b_rne(v.y); o.z = f2b_rne(v.z); o.w = f2b_rne(v.w);
  *(ushort4*)(E16 + i) = o;
}

// ---------------- kernel 0b: W1 (2048x512 f32) -> W16T (512x2048 bf16) ----------------
__global__ void k_cvt_w(const float* __restrict__ W1, u16* __restrict__ WT) {
  __shared__ float tile[64][65];
  int t = threadIdx.x;
  int kBase = blockIdx.x * 64;
  int chBase = blockIdx.y * 64;
  int lr = t >> 4, lc = (t & 15) * 4;
  for (int rr = 0; rr < 4; rr++) {
    int kr = lr + rr * 16;
    float4 v = *(const float4*)(W1 + (kBase + kr) * 512 + chBase + lc);
    tile[kr][lc] = v.x; tile[kr][lc + 1] = v.y;
    tile[kr][lc + 2] = v.z; tile[kr][lc + 3] = v.w;
  }
  __syncthreads();
  int ch = t >> 2, ks = (t & 3) * 16;
  u32 w[8];
  for (int u = 0; u < 8; u++) {
    u16 lo = f2b_rne(tile[ks + 2 * u][ch]);
    u16 hi = f2b_rne(tile[ks + 2 * u + 1][ch]);
    w[u] = (u32)lo | ((u32)hi << 16);
  }
  u16* dst = WT + (chBase + ch) * 2048 + kBase + ks;
  uint4 s0; s0.x = w[0]; s0.y = w[1]; s0.z = w[2]; s0.w = w[3];
  uint4 s1; s1.x = w[4]; s1.y = w[5]; s1.z = w[6]; s1.w = w[7];
  *(uint4*)(dst) = s0;
  *(uint4*)(dst + 8) = s1;
}

// ---------------- kernel 1: a = E@Wa, c = E@Wb ----------------
__global__ __launch_bounds__(256, 4) void k_ac(const u16* __restrict__ E16,
                                               const u16* __restrict__ WT,
                                               float* __restrict__ Aw,
                                               float* __restrict__ Cw) {
  __shared__ __align__(16) char smem[16384];
  char* sA = smem;
  char* sB = smem + 8192;
  const int tid = threadIdx.x;
  const int lane = tid & 63, wid = tid >> 6;
  const int wr = wid >> 1, wcl = wid & 1;
  const int n = lane & 31, q = lane >> 5;
  const int rowBase = blockIdx.y * 128;
  const int chBase = blockIdx.x * 128;
  const int halfOff = (chBase >= 512) ? 512 : 0;
  const int chSrc0 = chBase - halfOff;
  f32x16 acc[2][2];
  for (int a = 0; a < 2; a++)
    for (int c = 0; c < 2; c++)
      for (int e = 0; e < 16; e++) acc[a][c][e] = 0.f;
  for (int kc = 0; kc < 16; kc++) {
    const int k0 = kc * 32;
    __syncthreads();
    for (int s2 = 0; s2 < 2; s2++) {
      int s = tid * 2 + s2;
      int row = s >> 2, pg = s & 3, lg = pg ^ ((row >> 1) & 3);
      *(uint4*)(sA + row * 64 + lg * 16) =
          *(const uint4*)(E16 + (rowBase + row) * 512 + k0 + pg * 8);
      *(uint4*)(sB + row * 64 + lg * 16) =
          *(const uint4*)(WT + (chSrc0 + row) * 2048 + halfOff + k0 + pg * 8);
    }
    __syncthreads();
    for (int ks = 0; ks < 2; ks++) {
      int kg = ks * 2 + q;
      bf16x8 af[2], bfr[2];
      for (int rb = 0; rb < 2; rb++) {
        int row = wr * 64 + rb * 32 + n;
        af[rb] = *(const bf16x8*)(sA + row * 64 + ((kg ^ ((row >> 1) & 3)) * 16));
      }
      for (int cb = 0; cb < 2; cb++) {
        int ch = wcl * 64 + cb * 32 + n;
        bfr[cb] = *(const bf16x8*)(sB + ch * 64 + ((kg ^ ((ch >> 1) & 3)) * 16));
      }
      for (int rb = 0; rb < 2; rb++)
        for (int cb = 0; cb < 2; cb++)
          acc[rb][cb] = __builtin_amdgcn_mfma_f32_32x32x16_bf16(af[rb], bfr[cb],
                                                               acc[rb][cb], 0, 0, 0);
    }
  }
  for (int rb = 0; rb < 2; rb++)
    for (int cb = 0; cb < 2; cb++)
      for (int r = 0; r < 16; r++) {
        int rowl = (r & 3) + 8 * (r >> 2) + 4 * q;
        int rowg = rowBase + wr * 64 + rb * 32 + rowl;
        int chg = chBase + wcl * 64 + cb * 32 + n;
        float v = acc[rb][cb][r];
        if (chg < 512) Aw[rowg * 512 + chg] = v;
        else Cw[rowg * 512 + chg - 512] = v;
      }
}

// ---------------- kernel 2: pair kernel ----------------
// Block: 8 i x 16 j = 128 pairs, 256 thr (2x2 waves), 2 ch passes of 256,
// K=1024 in chunks of 32. e_i tile stored f32 (no va unpack), e_j bf16.
// A-fragments formed in-register with f32x2 packed math; B double-buffered
// via async global_load_lds; ONE raw s_barrier+vmcnt(0) per kc.
#define EIF_OFF 0            // 8 rows x 516 f32 (2064B) = 16512
#define EJ_OFF 16512         // 16 rows x 520 bf16 (1040B) = 16640 -> 33152
#define BB_OFF 33152         // 2 x 16384 -> 65920
#define CJB_OFF 49536        // epilogue alias over B buffer1 (16KB)
#define W2S_OFF 65920        // 1024 -> 66944
#define RED_OFF 66944        // 128*9*4 = 4608 -> 71552
#define SMEM2 71552

// acc[2][4]=128 AGPR + ~120 arch VGPR on unified RF: 2 waves/SIMD structural max.
__global__ __launch_bounds__(256, 2) void k_pair(
    const float* __restrict__ E, const u16* __restrict__ E16,
    const u16* __restrict__ WT,
    const float* __restrict__ Aw, const float* __restrict__ Cw,
    const float* __restrict__ b1, const float* __restrict__ w2,
    const float* __restrict__ b2, float* __restrict__ out) {
  __shared__ __align__(16) char smem[SMEM2];
  const int tid = threadIdx.x;
  const int lane = tid & 63, wid = tid >> 6;
  const int wr = wid >> 1, wcl = wid & 1;
  const int n = lane & 31, q = lane >> 5;
  const int bb = blockIdx.z;
  const int bi0 = blockIdx.y * 8;
  const int bj0 = blockIdx.x * 16;

  // async-stage one B tile [256 ch][32 k] into buffer nbuf (R4-proven layout)
  auto prefetch_B = [&](int npass, int nkc, int nbuf) {
    const int nch0 = npass * 256, nk0 = nkc * 32;
    char* base = smem + BB_OFF + nbuf * 16384 + wid * 4096;
    for (int t = 0; t < 4; t++) {
      int seg = wid * 4 + t;
      int row = seg * 16 + (lane >> 2);
      int pg = (lane & 3) ^ ((row >> 1) & 3);
      const u16* g = WT + (nch0 + row) * 2048 + 1024 + nk0 + pg * 8;
      __builtin_amdgcn_global_load_lds(
          (const __attribute__((address_space(1))) void*)g,
          (__attribute__((address_space(3))) void*)(base + t * 1024), 16, 0, 0);
    }
  };

  prefetch_B(0, 0, 0);

  // stage e_i tile as f32 straight from E (8 rows x 512)
  for (int s = tid; s < 1024; s += 256) {
    int row = s >> 7, c4 = s & 127;
    *(float4*)(smem + EIF_OFF + row * 2064 + c4 * 16) =
        *(const float4*)(E + (bb * 256 + bi0 + row) * 512 + c4 * 4);
  }
  // stage e_j tile bf16 (16 rows x 512)
  for (int s = tid; s < 1024; s += 256) {
    int row = s >> 6, c16 = s & 63;
    *(uint4*)(smem + EJ_OFF + row * 1040 + c16 * 16) =
        *(const uint4*)(E16 + (bb * 256 + bj0 + row) * 512 + c16 * 8);
  }
  __syncthreads();  // e-tiles visible; also drains first prefetch

  float* RED = (float*)(smem + RED_OFF);
  const float* eifA = (const float*)(smem + EIF_OFF) + (wr * 4 + (n >> 4)) * 516;
  const u16* ejp = (const u16*)(smem + EJ_OFF) + (n & 15) * 520;

  for (int pass = 0; pass < 2; pass++) {
    const int ch0 = pass * 256;
    f32x16 acc[2][4];
    for (int a = 0; a < 2; a++)
      for (int c = 0; c < 4; c++)
        for (int e = 0; e < 16; e++) acc[a][c][e] = 0.f;

    for (int kc = 0; kc < 32; kc++) {
      const int buf = kc & 1;
      asm volatile("s_waitcnt vmcnt(0)\n\ts_barrier" ::: "memory");
      int lcn = pass * 32 + kc + 1;
      if (lcn < 64) prefetch_B(lcn >> 5, lcn & 31, buf ^ 1);

      const int dBase = (kc * 32) & 511;
      const bool isV = kc >= 16;
      const char* B2 = smem + BB_OFF + buf * 16384;
      for (int ks = 0; ks < 2; ks++) {
        const int d0 = dBase + ks * 16 + q * 8;
        // shared vb (same for both rb): 8 bf16 -> f32 pairs
        uint4 bw = *(const uint4*)(ejp + d0);
        f32x2 b01, b23, b45, b67;
        b01.x = bflo(bw.x); b01.y = bfhi(bw.x);
        b23.x = bflo(bw.y); b23.y = bfhi(bw.y);
        b45.x = bflo(bw.z); b45.y = bfhi(bw.z);
        b67.x = bflo(bw.w); b67.y = bfhi(bw.w);
        bf16x8 af[2];
        for (int rb = 0; rb < 2; rb++) {
          const float* ai = eifA + rb * 1032 + d0;  // 2*516 f32 row step
          float4 x0 = *(const float4*)(ai);
          float4 x1 = *(const float4*)(ai + 4);
          f32x2 a01; a01.x = x0.x; a01.y = x0.y;
          f32x2 a23; a23.x = x0.z; a23.y = x0.w;
          f32x2 a45; a45.x = x1.x; a45.y = x1.y;
          f32x2 a67; a67.x = x1.z; a67.y = x1.w;
          uint4 ov;
          if (!isV) {
            ov.x = packpair(a01 * b01);
            ov.y = packpair(a23 * b23);
            ov.z = packpair(a45 * b45);
            ov.w = packpair(a67 * b67);
          } else {
            f32x2 d0v = a01 - b01, d1v = a23 - b23;
            f32x2 d2v = a45 - b45, d3v = a67 - b67;
            ov.x = packpair(__builtin_elementwise_max(d0v, -d0v));
            ov.y = packpair(__builtin_elementwise_max(d1v, -d1v));
            ov.z = packpair(__builtin_elementwise_max(d2v, -d2v));
            ov.w = packpair(__builtin_elementwise_max(d3v, -d3v));
          }
          af[rb] = __builtin_bit_cast(bf16x8, ov);
        }
        const int kg = ks * 2 + q;
        bf16x8 bfr[4];
        for (int cb = 0; cb < 4; cb++) {
          int ch = wcl * 128 + cb * 32 + n;
          bfr[cb] = *(const bf16x8*)(B2 + ch * 64 + ((kg ^ ((ch >> 1) & 3)) * 16));
        }
        for (int rb = 0; rb < 2; rb++)
          for (int cb = 0; cb < 4; cb++)
            acc[rb][cb] = __builtin_amdgcn_mfma_f32_32x32x16_bf16(af[rb], bfr[cb],
                                                                 acc[rb][cb], 0, 0, 0);
      }
    }

    // ---- epilogue for this pass ----
    __syncthreads();
    {
      float b1v = b1[ch0 + tid];
      for (int j = 0; j < 16; j++)
        *(float*)(smem + CJB_OFF + (j * 256 + tid) * 4) =
            Cw[(bb * 256 + bj0 + j) * 512 + ch0 + tid] + b1v;
      *(float*)(smem + W2S_OFF + tid * 4) = w2[ch0 + tid];
    }
    __syncthreads();

    const float* CJB = (const float*)(smem + CJB_OFF);
    const float* W2S = (const float*)(smem + W2S_OFF);
    for (int rb = 0; rb < 2; rb++) {
      float av[4][2], w2v[4];
      int chls[4];
      for (int cb = 0; cb < 4; cb++) {
        int chl = wcl * 128 + cb * 32 + n;
        chls[cb] = chl;
        w2v[cb] = W2S[chl];
        int irow = bb * 256 + bi0 + wr * 4 + rb * 2;
        av[cb][0] = Aw[irow * 512 + ch0 + chl];
        av[cb][1] = Aw[(irow + 1) * 512 + ch0 + chl];
      }
      for (int r = 0; r < 16; r++) {
        int rowl = (r & 3) + 8 * (r >> 2) + 4 * q;  // C/D layout (m74/m101)
        int j = rowl & 15;
        int hi = r >> 3;
        float v = 0.f;
        for (int cb = 0; cb < 4; cb++) {
          float h = acc[rb][cb][r] + av[cb][hi] + CJB[j * 256 + chls[cb]];
          if (h > 0.f) v += h * w2v[cb];
        }
        v += __shfl_xor(v, 1);
        v += __shfl_xor(v, 2);
        v += __shfl_xor(v, 4);
        if ((n & 7) == 0) {
          int p = wr * 64 + rb * 32 + rowl;
          int slot = p * 9 + wcl * 4 + (n >> 3);
          if (pass == 0) RED[slot] = v;
          else RED[slot] += v;
        }
      }
    }
  }

  __syncthreads();
  if (tid < 128) {
    float s = b2[0];
    for (int u = 0; u < 8; u++) s += RED[tid * 9 + u];
    out[(bb * 256 + bi0 + (tid >> 4)) * 256 + bj0 + (tid & 15)] = s;
  }
}

// ---------------- launcher ----------------
extern "C" void kernel_launch(void* const* d_in, const int* in_sizes, int n_in,
                              void* d_out, int out_size, void* d_ws, size_t ws_size,
                              hipStream_t stream) {
  const float* E = (const float*)d_in[0];
  const float* W1 = (const float*)d_in[1];
  const float* b1 = (const float*)d_in[2];
  const float* W2 = (const float*)d_in[3];
  const float* b2 = (const float*)d_in[4];
  float* out = (float*)d_out;
  char* ws = (char*)d_ws;
  u16* E16 = (u16*)(ws + WS_E16);
  u16* WT = (u16*)(ws + WS_WT);
  float* Aw = (float*)(ws + WS_A);
  float* Cw = (float*)(ws + WS_C);

  hipLaunchKernelGGL(k_cvt_e, dim3(512), dim3(256), 0, stream, E, E16);
  hipLaunchKernelGGL(k_cvt_w, dim3(32, 8), dim3(256), 0, stream, W1, WT);
  hipLaunchKernelGGL(k_ac, dim3(8, 8), dim3(256), 0, stream, E16, WT, Aw, Cw);
  hipLaunchKernelGGL(k_pair, dim3(16, 32, 4), dim3(256), 0, stream,
                     E, E16, WT, Aw, Cw, b1, W2, b2, out);
}

// Round 7
// 316.678 us; speedup vs baseline: 2.5723x; 1.3960x over previous
//
#include <hip/hip_runtime.h>
#include <stdint.h>

typedef unsigned int u32;
typedef unsigned short u16;
typedef __attribute__((ext_vector_type(8))) short bf16x8;
typedef __attribute__((ext_vector_type(16))) float f32x16;
typedef __attribute__((ext_vector_type(2))) float f32x2;

#define DEVI __device__ __forceinline__

// ---------------- numeric helpers ----------------
DEVI u16 f2b_rne(float f) {
  u32 u = __float_as_uint(f);
  u += 0x7FFFu + ((u >> 16) & 1u);
  return (u16)(u >> 16);
}
// pack truncated bf16 of two f32: [bf16(v.y)][bf16(v.x)]
DEVI u32 packpair(f32x2 v) {
  return __builtin_amdgcn_perm(__float_as_uint(v.y), __float_as_uint(v.x),
                               0x07060302u);
}
DEVI float bflo(u32 w) { return __uint_as_float(w << 16); }
DEVI float bfhi(u32 w) { return __uint_as_float(w & 0xFFFF0000u); }

// ---------------- ws layout (bytes) ----------------
#define WS_E16 0
#define WS_WT (1u << 20)
#define WS_A (3u << 20)
#define WS_C (5u << 20)

// ---------------- kernel 0a: E -> bf16 ----------------
__global__ void k_cvt_e(const float* __restrict__ E, u16* __restrict__ E16) {
  int i = (blockIdx.x * blockDim.x + threadIdx.x) * 4;
  float4 v = *(const float4*)(E + i);
  ushort4 o;
  o.x = f2b_rne(v.x); o.y = f2b_rne(v.y); o.z = f2b_rne(v.z); o.w = f2b_rne(v.w);
  *(ushort4*)(E16 + i) = o;
}

// ---------------- kernel 0b: W1 (2048x512 f32) -> W16T (512x2048 bf16) ----------------
__global__ void k_cvt_w(const float* __restrict__ W1, u16* __restrict__ WT) {
  __shared__ float tile[64][65];
  int t = threadIdx.x;
  int kBase = blockIdx.x * 64;
  int chBase = blockIdx.y * 64;
  int lr = t >> 4, lc = (t & 15) * 4;
  for (int rr = 0; rr < 4; rr++) {
    int kr = lr + rr * 16;
    float4 v = *(const float4*)(W1 + (kBase + kr) * 512 + chBase + lc);
    tile[kr][lc] = v.x; tile[kr][lc + 1] = v.y;
    tile[kr][lc + 2] = v.z; tile[kr][lc + 3] = v.w;
  }
  __syncthreads();
  int ch = t >> 2, ks = (t & 3) * 16;
  u32 w[8];
  for (int u = 0; u < 8; u++) {
    u16 lo = f2b_rne(tile[ks + 2 * u][ch]);
    u16 hi = f2b_rne(tile[ks + 2 * u + 1][ch]);
    w[u] = (u32)lo | ((u32)hi << 16);
  }
  u16* dst = WT + (chBase + ch) * 2048 + kBase + ks;
  uint4 s0; s0.x = w[0]; s0.y = w[1]; s0.z = w[2]; s0.w = w[3];
  uint4 s1; s1.x = w[4]; s1.y = w[5]; s1.z = w[6]; s1.w = w[7];
  *(uint4*)(dst) = s0;
  *(uint4*)(dst + 8) = s1;
}

// ---------------- kernel 1: a = E@Wa, c = E@Wb ----------------
__global__ __launch_bounds__(256, 4) void k_ac(const u16* __restrict__ E16,
                                               const u16* __restrict__ WT,
                                               float* __restrict__ Aw,
                                               float* __restrict__ Cw) {
  __shared__ __align__(16) char smem[16384];
  char* sA = smem;
  char* sB = smem + 8192;
  const int tid = threadIdx.x;
  const int lane = tid & 63, wid = tid >> 6;
  const int wr = wid >> 1, wcl = wid & 1;
  const int n = lane & 31, q = lane >> 5;
  const int rowBase = blockIdx.y * 128;
  const int chBase = blockIdx.x * 128;
  const int halfOff = (chBase >= 512) ? 512 : 0;
  const int chSrc0 = chBase - halfOff;
  f32x16 acc[2][2];
  for (int a = 0; a < 2; a++)
    for (int c = 0; c < 2; c++)
      for (int e = 0; e < 16; e++) acc[a][c][e] = 0.f;
  for (int kc = 0; kc < 16; kc++) {
    const int k0 = kc * 32;
    __syncthreads();
    for (int s2 = 0; s2 < 2; s2++) {
      int s = tid * 2 + s2;
      int row = s >> 2, pg = s & 3, lg = pg ^ ((row >> 1) & 3);
      *(uint4*)(sA + row * 64 + lg * 16) =
          *(const uint4*)(E16 + (rowBase + row) * 512 + k0 + pg * 8);
      *(uint4*)(sB + row * 64 + lg * 16) =
          *(const uint4*)(WT + (chSrc0 + row) * 2048 + halfOff + k0 + pg * 8);
    }
    __syncthreads();
    for (int ks = 0; ks < 2; ks++) {
      int kg = ks * 2 + q;
      bf16x8 af[2], bfr[2];
      for (int rb = 0; rb < 2; rb++) {
        int row = wr * 64 + rb * 32 + n;
        af[rb] = *(const bf16x8*)(sA + row * 64 + ((kg ^ ((row >> 1) & 3)) * 16));
      }
      for (int cb = 0; cb < 2; cb++) {
        int ch = wcl * 64 + cb * 32 + n;
        bfr[cb] = *(const bf16x8*)(sB + ch * 64 + ((kg ^ ((ch >> 1) & 3)) * 16));
      }
      for (int rb = 0; rb < 2; rb++)
        for (int cb = 0; cb < 2; cb++)
          acc[rb][cb] = __builtin_amdgcn_mfma_f32_32x32x16_bf16(af[rb], bfr[cb],
                                                               acc[rb][cb], 0, 0, 0);
    }
  }
  for (int rb = 0; rb < 2; rb++)
    for (int cb = 0; cb < 2; cb++)
      for (int r = 0; r < 16; r++) {
        int rowl = (r & 3) + 8 * (r >> 2) + 4 * q;
        int rowg = rowBase + wr * 64 + rb * 32 + rowl;
        int chg = chBase + wcl * 64 + cb * 32 + n;
        float v = acc[rb][cb][r];
        if (chg < 512) Aw[rowg * 512 + chg] = v;
        else Cw[rowg * 512 + chg - 512] = v;
      }
}

// ---------------- kernel 2: pair kernel (symmetric-tile, atomic combine) ----
// P(i,j) = (ei*ej)@Wc + |ei-ej|@Wd is SYMMETRIC in (i,j). Only pair-tiles
// intersecting the upper triangle are launched (272 of 512); each emits
// score(i,j) = relu(P+a_i+c_j+b1).w2  AND  score(j,i) = relu(P+a_j+c_i+b1).w2.
// Channel halves are SEPARATE blocks (blockIdx.y): since relu is per-channel,
// each half's contribution is independent -> atomicAdd into zeroed out
// (R6 bug: plain stores raced between the two halves). Exactly 2 atomics per
// entry, float add commutative -> deterministic.
#define EIF_OFF 0            // 8 rows x 516 f32 (2064B) = 16512
#define EJ_OFF 16512         // 16 rows x 520 bf16 (1040B) = 16640 -> 33152
#define BB_OFF 33152         // 2 x 16384 -> 65920
#define AJB_OFF 33152        // epilogue alias over B buf0 (16*256*4 = 16KB)
#define CJB_OFF 49536        // epilogue alias over B buf1 (16KB)
#define W2S_OFF 65920        // 1024 -> 66944
#define RED_OFF 66944        // 128*9*4 = 4608 -> 71552
#define RED2_OFF 71552       // 4608 -> 76160
#define SMEM2 76160

// acc[2][4]=128 AGPR + ~125 arch VGPR on unified RF: 2 waves/SIMD structural max.
__global__ __launch_bounds__(256, 2) void k_pair(
    const float* __restrict__ E, const u16* __restrict__ E16,
    const u16* __restrict__ WT,
    const float* __restrict__ Aw, const float* __restrict__ Cw,
    const float* __restrict__ b1, const float* __restrict__ w2,
    const float* __restrict__ b2, float* __restrict__ out) {
  __shared__ __align__(16) char smem[SMEM2];
  const int tid = threadIdx.x;
  const int lane = tid & 63, wid = tid >> 6;
  const int wr = wid >> 1, wcl = wid & 1;
  const int n = lane & 31, q = lane >> 5;
  const int bb = blockIdx.z;
  const int ch0 = blockIdx.y * 256;

  // invert triangular tile index: f = tj*(tj+1) + ti, ti in [0, 2*tj+2)
  int f = blockIdx.x;
  int tj = (int)((__builtin_sqrtf(4.0f * (float)f + 1.0f) - 1.0f) * 0.5f);
  while ((tj + 1) * (tj + 2) <= f) tj++;
  while (tj * (tj + 1) > f) tj--;
  const int ti = f - tj * (tj + 1);
  const int bi0 = ti * 8;
  const int bj0 = tj * 16;

  // async-stage one B tile [256 ch][32 k] into buffer nbuf (R4-proven layout)
  auto prefetch_B = [&](int nkc, int nbuf) {
    const int nk0 = nkc * 32;
    char* base = smem + BB_OFF + nbuf * 16384 + wid * 4096;
    for (int t = 0; t < 4; t++) {
      int seg = wid * 4 + t;
      int row = seg * 16 + (lane >> 2);
      int pg = (lane & 3) ^ ((row >> 1) & 3);
      const u16* g = WT + (ch0 + row) * 2048 + 1024 + nk0 + pg * 8;
      __builtin_amdgcn_global_load_lds(
          (const __attribute__((address_space(1))) void*)g,
          (__attribute__((address_space(3))) void*)(base + t * 1024), 16, 0, 0);
    }
  };

  prefetch_B(0, 0);

  // stage e_i tile as f32 straight from E (8 rows x 512)
  for (int s = tid; s < 1024; s += 256) {
    int row = s >> 7, c4 = s & 127;
    *(float4*)(smem + EIF_OFF + row * 2064 + c4 * 16) =
        *(const float4*)(E + (bb * 256 + bi0 + row) * 512 + c4 * 4);
  }
  // stage e_j tile bf16 (16 rows x 512)
  for (int s = tid; s < 1024; s += 256) {
    int row = s >> 6, c16 = s & 63;
    *(uint4*)(smem + EJ_OFF + row * 1040 + c16 * 16) =
        *(const uint4*)(E16 + (bb * 256 + bj0 + row) * 512 + c16 * 8);
  }
  __syncthreads();  // e-tiles visible; also drains first prefetch

  const float* eifA = (const float*)(smem + EIF_OFF) + (wr * 4 + (n >> 4)) * 516;
  const u16* ejp = (const u16*)(smem + EJ_OFF) + (n & 15) * 520;

  f32x16 acc[2][4];
  for (int a = 0; a < 2; a++)
    for (int c = 0; c < 4; c++)
      for (int e = 0; e < 16; e++) acc[a][c][e] = 0.f;

  for (int kc = 0; kc < 32; kc++) {
    const int buf = kc & 1;
    asm volatile("s_waitcnt vmcnt(0)\n\ts_barrier" ::: "memory");
    if (kc + 1 < 32) prefetch_B(kc + 1, buf ^ 1);

    const int dBase = (kc * 32) & 511;
    const bool isV = kc >= 16;
    const char* B2 = smem + BB_OFF + buf * 16384;
    for (int ks = 0; ks < 2; ks++) {
      const int d0 = dBase + ks * 16 + q * 8;
      // shared vb (same for both rb): 8 bf16 -> f32 pairs
      uint4 bw = *(const uint4*)(ejp + d0);
      f32x2 b01, b23, b45, b67;
      b01.x = bflo(bw.x); b01.y = bfhi(bw.x);
      b23.x = bflo(bw.y); b23.y = bfhi(bw.y);
      b45.x = bflo(bw.z); b45.y = bfhi(bw.z);
      b67.x = bflo(bw.w); b67.y = bfhi(bw.w);
      bf16x8 af[2];
      for (int rb = 0; rb < 2; rb++) {
        const float* ai = eifA + rb * 1032 + d0;  // 2*516 f32 row step
        float4 x0 = *(const float4*)(ai);
        float4 x1 = *(const float4*)(ai + 4);
        f32x2 a01; a01.x = x0.x; a01.y = x0.y;
        f32x2 a23; a23.x = x0.z; a23.y = x0.w;
        f32x2 a45; a45.x = x1.x; a45.y = x1.y;
        f32x2 a67; a67.x = x1.z; a67.y = x1.w;
        uint4 ov;
        if (!isV) {
          ov.x = packpair(a01 * b01);
          ov.y = packpair(a23 * b23);
          ov.z = packpair(a45 * b45);
          ov.w = packpair(a67 * b67);
        } else {
          f32x2 d0v = a01 - b01, d1v = a23 - b23;
          f32x2 d2v = a45 - b45, d3v = a67 - b67;
          ov.x = packpair(__builtin_elementwise_max(d0v, -d0v));
          ov.y = packpair(__builtin_elementwise_max(d1v, -d1v));
          ov.z = packpair(__builtin_elementwise_max(d2v, -d2v));
          ov.w = packpair(__builtin_elementwise_max(d3v, -d3v));
        }
        af[rb] = __builtin_bit_cast(bf16x8, ov);
      }
      const int kg = ks * 2 + q;
      bf16x8 bfr[4];
      for (int cb = 0; cb < 4; cb++) {
        int ch = wcl * 128 + cb * 32 + n;
        bfr[cb] = *(const bf16x8*)(B2 + ch * 64 + ((kg ^ ((ch >> 1) & 3)) * 16));
      }
      for (int rb = 0; rb < 2; rb++)
        for (int cb = 0; cb < 4; cb++)
          acc[rb][cb] = __builtin_amdgcn_mfma_f32_32x32x16_bf16(af[rb], bfr[cb],
                                                               acc[rb][cb], 0, 0, 0);
    }
  }

  // ---- epilogue: emit fwd (i,j) and transposed (j,i) partial scores ----
  __syncthreads();  // all waves done with both B buffers
  {
    float b1v = b1[ch0 + tid];
    for (int j = 0; j < 16; j++) {
      int grow = (bb * 256 + bj0 + j) * 512 + ch0 + tid;
      *(float*)(smem + CJB_OFF + (j * 256 + tid) * 4) = Cw[grow] + b1v;
      *(float*)(smem + AJB_OFF + (j * 256 + tid) * 4) = Aw[grow] + b1v;
    }
    *(float*)(smem + W2S_OFF + tid * 4) = w2[ch0 + tid];
  }
  __syncthreads();

  float* RED = (float*)(smem + RED_OFF);
  float* RED2 = (float*)(smem + RED2_OFF);
  const float* CJB = (const float*)(smem + CJB_OFF);
  const float* AJB = (const float*)(smem + AJB_OFF);
  const float* W2S = (const float*)(smem + W2S_OFF);
  for (int rb = 0; rb < 2; rb++) {
    float av[4][2], civ[4][2], w2v[4];
    int chls[4];
    for (int cb = 0; cb < 4; cb++) {
      int chl = wcl * 128 + cb * 32 + n;
      chls[cb] = chl;
      w2v[cb] = W2S[chl];
      int irow = (bb * 256 + bi0 + wr * 4 + rb * 2) * 512 + ch0 + chl;
      av[cb][0] = Aw[irow];
      av[cb][1] = Aw[irow + 512];
      civ[cb][0] = Cw[irow];
      civ[cb][1] = Cw[irow + 512];
    }
    for (int r = 0; r < 16; r++) {
      int rowl = (r & 3) + 8 * (r >> 2) + 4 * q;  // C/D layout (m74/m101)
      int j = rowl & 15;
      int hi = r >> 3;
      float vf = 0.f, vt = 0.f;
      for (int cb = 0; cb < 4; cb++) {
        float base = acc[rb][cb][r];
        float hf = base + av[cb][hi] + CJB[j * 256 + chls[cb]];
        if (hf > 0.f) vf += hf * w2v[cb];
        float ht = base + civ[cb][hi] + AJB[j * 256 + chls[cb]];
        if (ht > 0.f) vt += ht * w2v[cb];
      }
      vf += __shfl_xor(vf, 1); vt += __shfl_xor(vt, 1);
      vf += __shfl_xor(vf, 2); vt += __shfl_xor(vt, 2);
      vf += __shfl_xor(vf, 4); vt += __shfl_xor(vt, 4);
      if ((n & 7) == 0) {
        int p = wr * 64 + rb * 32 + rowl;
        int slot = p * 9 + wcl * 4 + (n >> 3);
        RED[slot] = vf;
        RED2[slot] = vt;
      }
    }
  }

  __syncthreads();
  {
    int p = tid & 127;
    int gi = bi0 + (p >> 4), gj = bj0 + (p & 15);
    float half_b2 = 0.5f * b2[0];  // each ch-half block contributes half of b2
    if (tid < 128) {
      float s = half_b2;
      for (int u = 0; u < 8; u++) s += RED[p * 9 + u];
      if (gi <= gj) atomicAdd(out + (bb * 256 + gi) * 256 + gj, s);
    } else {
      float s = half_b2;
      for (int u = 0; u < 8; u++) s += RED2[p * 9 + u];
      if (gi < gj) atomicAdd(out + (bb * 256 + gj) * 256 + gi, s);
    }
  }
}

// ---------------- launcher ----------------
extern "C" void kernel_launch(void* const* d_in, const int* in_sizes, int n_in,
                              void* d_out, int out_size, void* d_ws, size_t ws_size,
                              hipStream_t stream) {
  const float* E = (const float*)d_in[0];
  const float* W1 = (const float*)d_in[1];
  const float* b1 = (const float*)d_in[2];
  const float* W2 = (const float*)d_in[3];
  const float* b2 = (const float*)d_in[4];
  float* out = (float*)d_out;
  char* ws = (char*)d_ws;
  u16* E16 = (u16*)(ws + WS_E16);
  u16* WT = (u16*)(ws + WS_WT);
  float* Aw = (float*)(ws + WS_A);
  float* Cw = (float*)(ws + WS_C);

  // out accumulated via atomicAdd from the two channel-half blocks: zero first
  hipMemsetAsync(out, 0, (size_t)out_size * sizeof(float), stream);
  hipLaunchKernelGGL(k_cvt_e, dim3(512), dim3(256), 0, stream, E, E16);
  hipLaunchKernelGGL(k_cvt_w, dim3(32, 8), dim3(256), 0, stream, W1, WT);
  hipLaunchKernelGGL(k_ac, dim3(8, 8), dim3(256), 0, stream, E16, WT, Aw, Cw);
  // 272 = # of 8x16 pair-tiles intersecting the upper triangle (tj*(tj+1)+ti)
  hipLaunchKernelGGL(k_pair, dim3(272, 2, 4), dim3(256), 0, stream,
                     E, E16, WT, Aw, Cw, b1, W2, b2, out);
}

// Round 8
// 279.674 us; speedup vs baseline: 2.9127x; 1.1323x over previous
//
#include <hip/hip_runtime.h>
#include <stdint.h>

typedef unsigned int u32;
typedef unsigned short u16;
typedef __attribute__((ext_vector_type(8))) short bf16x8;
typedef __attribute__((ext_vector_type(16))) float f32x16;
typedef __attribute__((ext_vector_type(2))) float f32x2;

#define DEVI __device__ __forceinline__

// ---------------- numeric helpers ----------------
DEVI u16 f2b_rne(float f) {
  u32 u = __float_as_uint(f);
  u += 0x7FFFu + ((u >> 16) & 1u);
  return (u16)(u >> 16);
}
// pack truncated bf16 of two f32: [bf16(v.y)][bf16(v.x)]
DEVI u32 packpair(f32x2 v) {
  return __builtin_amdgcn_perm(__float_as_uint(v.y), __float_as_uint(v.x),
                               0x07060302u);
}
DEVI float bflo(u32 w) { return __uint_as_float(w << 16); }
DEVI float bfhi(u32 w) { return __uint_as_float(w & 0xFFFF0000u); }

// ---------------- ws layout (bytes) ----------------
#define WS_E16 0
#define WS_WT (1u << 20)
#define WS_A (3u << 20)
#define WS_C (5u << 20)

// ---------------- kernel 0: fused E->bf16 (blocks 0..511) and
//                  W1 (2048x512 f32) -> W16T (512x2048 bf16) (blocks 512..767)
__global__ void k_cvt(const float* __restrict__ E, u16* __restrict__ E16,
                      const float* __restrict__ W1, u16* __restrict__ WT) {
  __shared__ float tile[64][65];
  if (blockIdx.x < 512) {
    int i = (blockIdx.x * blockDim.x + threadIdx.x) * 4;
    float4 v = *(const float4*)(E + i);
    ushort4 o;
    o.x = f2b_rne(v.x); o.y = f2b_rne(v.y); o.z = f2b_rne(v.z); o.w = f2b_rne(v.w);
    *(ushort4*)(E16 + i) = o;
    return;
  }
  int bid = blockIdx.x - 512;
  int t = threadIdx.x;
  int kBase = (bid & 31) * 64;   // 32 k-tiles
  int chBase = (bid >> 5) * 64;  // 8 ch-tiles
  int lr = t >> 4, lc = (t & 15) * 4;
  for (int rr = 0; rr < 4; rr++) {
    int kr = lr + rr * 16;
    float4 v = *(const float4*)(W1 + (kBase + kr) * 512 + chBase + lc);
    tile[kr][lc] = v.x; tile[kr][lc + 1] = v.y;
    tile[kr][lc + 2] = v.z; tile[kr][lc + 3] = v.w;
  }
  __syncthreads();
  int ch = t >> 2, ks = (t & 3) * 16;
  u32 w[8];
  for (int u = 0; u < 8; u++) {
    u16 lo = f2b_rne(tile[ks + 2 * u][ch]);
    u16 hi = f2b_rne(tile[ks + 2 * u + 1][ch]);
    w[u] = (u32)lo | ((u32)hi << 16);
  }
  u16* dst = WT + (chBase + ch) * 2048 + kBase + ks;
  uint4 s0; s0.x = w[0]; s0.y = w[1]; s0.z = w[2]; s0.w = w[3];
  uint4 s1; s1.x = w[4]; s1.y = w[5]; s1.z = w[6]; s1.w = w[7];
  *(uint4*)(dst) = s0;
  *(uint4*)(dst + 8) = s1;
}

// ---------------- kernel 1: a = E@Wa, c = E@Wb ----------------
__global__ __launch_bounds__(256, 4) void k_ac(const u16* __restrict__ E16,
                                               const u16* __restrict__ WT,
                                               float* __restrict__ Aw,
                                               float* __restrict__ Cw) {
  __shared__ __align__(16) char smem[16384];
  char* sA = smem;
  char* sB = smem + 8192;
  const int tid = threadIdx.x;
  const int lane = tid & 63, wid = tid >> 6;
  const int wr = wid >> 1, wcl = wid & 1;
  const int n = lane & 31, q = lane >> 5;
  const int rowBase = blockIdx.y * 128;
  const int chBase = blockIdx.x * 128;
  const int halfOff = (chBase >= 512) ? 512 : 0;
  const int chSrc0 = chBase - halfOff;
  f32x16 acc[2][2];
  for (int a = 0; a < 2; a++)
    for (int c = 0; c < 2; c++)
      for (int e = 0; e < 16; e++) acc[a][c][e] = 0.f;
  for (int kc = 0; kc < 16; kc++) {
    const int k0 = kc * 32;
    __syncthreads();
    for (int s2 = 0; s2 < 2; s2++) {
      int s = tid * 2 + s2;
      int row = s >> 2, pg = s & 3, lg = pg ^ ((row >> 1) & 3);
      *(uint4*)(sA + row * 64 + lg * 16) =
          *(const uint4*)(E16 + (rowBase + row) * 512 + k0 + pg * 8);
      *(uint4*)(sB + row * 64 + lg * 16) =
          *(const uint4*)(WT + (chSrc0 + row) * 2048 + halfOff + k0 + pg * 8);
    }
    __syncthreads();
    for (int ks = 0; ks < 2; ks++) {
      int kg = ks * 2 + q;
      bf16x8 af[2], bfr[2];
      for (int rb = 0; rb < 2; rb++) {
        int row = wr * 64 + rb * 32 + n;
        af[rb] = *(const bf16x8*)(sA + row * 64 + ((kg ^ ((row >> 1) & 3)) * 16));
      }
      for (int cb = 0; cb < 2; cb++) {
        int ch = wcl * 64 + cb * 32 + n;
        bfr[cb] = *(const bf16x8*)(sB + ch * 64 + ((kg ^ ((ch >> 1) & 3)) * 16));
      }
      for (int rb = 0; rb < 2; rb++)
        for (int cb = 0; cb < 2; cb++)
          acc[rb][cb] = __builtin_amdgcn_mfma_f32_32x32x16_bf16(af[rb], bfr[cb],
                                                               acc[rb][cb], 0, 0, 0);
    }
  }
  for (int rb = 0; rb < 2; rb++)
    for (int cb = 0; cb < 2; cb++)
      for (int r = 0; r < 16; r++) {
        int rowl = (r & 3) + 8 * (r >> 2) + 4 * q;
        int rowg = rowBase + wr * 64 + rb * 32 + rowl;
        int chg = chBase + wcl * 64 + cb * 32 + n;
        float v = acc[rb][cb][r];
        if (chg < 512) Aw[rowg * 512 + chg] = v;
        else Cw[rowg * 512 + chg - 512] = v;
      }
}

// ---------------- kernel 2: pair kernel (symmetric tiles, interleaved u/v) --
// P(i,j) symmetric -> triangular tiles (272 of 512), dual epilogue, atomic
// combine of the two channel-half blocks (blockIdx.y) into zeroed out.
// K-mapping INTERLEAVED: lk even = u-chunk d=(lk>>1)*32 (ei*ej), lk odd =
// v-chunk same d (|ei-ej|). One e-read forms BOTH fragment sets; v-frags are
// held in regs one phase (+16 VGPR). u-phase: formation + 16 MFMA (buf0);
// v-phase: pure bfr->MFMA burst (buf1). One raw s_barrier+vmcnt(0) per phase,
// depth-1 async global_load_lds prefetch (R4-proven).
#define EIF_OFF 0            // 8 rows x 516 f32 (2064B) = 16512
#define EJ_OFF 16512         // 16 rows x 520 bf16 (1040B) = 16640 -> 33152
#define BB_OFF 33152         // 2 x 16384 -> 65920
#define AJB_OFF 33152        // epilogue alias over B buf0 (16*256*4 = 16KB)
#define CJB_OFF 49536        // epilogue alias over B buf1 (16KB)
#define W2S_OFF 65920        // 1024 -> 66944
#define RED_OFF 66944        // 128*9*4 = 4608 -> 71552
#define RED2_OFF 71552       // 4608 -> 76160
#define SMEM2 76160

// acc[2][4]=128 AGPR + ~124 arch VGPR (incl. afv hold) <= 256: 2 waves/SIMD.
__global__ __launch_bounds__(256, 2) void k_pair(
    const float* __restrict__ E, const u16* __restrict__ E16,
    const u16* __restrict__ WT,
    const float* __restrict__ Aw, const float* __restrict__ Cw,
    const float* __restrict__ b1, const float* __restrict__ w2,
    const float* __restrict__ b2, float* __restrict__ out) {
  __shared__ __align__(16) char smem[SMEM2];
  const int tid = threadIdx.x;
  const int lane = tid & 63, wid = tid >> 6;
  const int wr = wid >> 1, wcl = wid & 1;
  const int n = lane & 31, q = lane >> 5;
  const int bb = blockIdx.z;
  const int ch0 = blockIdx.y * 256;

  // invert triangular tile index: f = tj*(tj+1) + ti, ti in [0, 2*tj+2)
  int f = blockIdx.x;
  int tj = (int)((__builtin_sqrtf(4.0f * (float)f + 1.0f) - 1.0f) * 0.5f);
  while ((tj + 1) * (tj + 2) <= f) tj++;
  while (tj * (tj + 1) > f) tj--;
  const int ti = f - tj * (tj + 1);
  const int bi0 = ti * 8;
  const int bj0 = tj * 16;

  // async-stage B tile lk: [256 ch][32 k], k-col = 1024 + (lk>>1)*32 + (lk&1)*512
  auto prefetch_B = [&](int lk, int nbuf) {
    const int col0 = 1024 + ((lk >> 1) << 5) + ((lk & 1) << 9);
    char* base = smem + BB_OFF + nbuf * 16384 + wid * 4096;
    for (int t = 0; t < 4; t++) {
      int seg = wid * 4 + t;
      int row = seg * 16 + (lane >> 2);
      int pg = (lane & 3) ^ ((row >> 1) & 3);
      const u16* g = WT + (ch0 + row) * 2048 + col0 + pg * 8;
      __builtin_amdgcn_global_load_lds(
          (const __attribute__((address_space(1))) void*)g,
          (__attribute__((address_space(3))) void*)(base + t * 1024), 16, 0, 0);
    }
  };

  prefetch_B(0, 0);

  // stage e_i tile as f32 straight from E (8 rows x 512)
  for (int s = tid; s < 1024; s += 256) {
    int row = s >> 7, c4 = s & 127;
    *(float4*)(smem + EIF_OFF + row * 2064 + c4 * 16) =
        *(const float4*)(E + (bb * 256 + bi0 + row) * 512 + c4 * 4);
  }
  // stage e_j tile bf16 (16 rows x 512)
  for (int s = tid; s < 1024; s += 256) {
    int row = s >> 6, c16 = s & 63;
    *(uint4*)(smem + EJ_OFF + row * 1040 + c16 * 16) =
        *(const uint4*)(E16 + (bb * 256 + bj0 + row) * 512 + c16 * 8);
  }
  __syncthreads();  // e-tiles visible; also drains first prefetch

  const float* eifA = (const float*)(smem + EIF_OFF) + (wr * 4 + (n >> 4)) * 516;
  const u16* ejp = (const u16*)(smem + EJ_OFF) + (n & 15) * 520;

  f32x16 acc[2][4];
  for (int a = 0; a < 2; a++)
    for (int c = 0; c < 4; c++)
      for (int e = 0; e < 16; e++) acc[a][c][e] = 0.f;

  bf16x8 afv[2][2];  // held v-fragments [ks][rb]
  for (int m = 0; m < 16; m++) {
    const int dBase = m * 32;
    // ---- u-phase: B tile lk=2m in buf0 ----
    asm volatile("s_waitcnt vmcnt(0)\n\ts_barrier" ::: "memory");
    prefetch_B(2 * m + 1, 1);
    {
      const char* B2 = smem + BB_OFF;
#pragma unroll
      for (int ks = 0; ks < 2; ks++) {
        const int d0 = dBase + ks * 16 + q * 8;
        uint4 bw = *(const uint4*)(ejp + d0);
        f32x2 b01, b23, b45, b67;
        b01.x = bflo(bw.x); b01.y = bfhi(bw.x);
        b23.x = bflo(bw.y); b23.y = bfhi(bw.y);
        b45.x = bflo(bw.z); b45.y = bfhi(bw.z);
        b67.x = bflo(bw.w); b67.y = bfhi(bw.w);
        bf16x8 afu[2];
#pragma unroll
        for (int rb = 0; rb < 2; rb++) {
          const float* ai = eifA + rb * 1032 + d0;  // 2*516 f32 row step
          float4 x0 = *(const float4*)(ai);
          float4 x1 = *(const float4*)(ai + 4);
          f32x2 a01; a01.x = x0.x; a01.y = x0.y;
          f32x2 a23; a23.x = x0.z; a23.y = x0.w;
          f32x2 a45; a45.x = x1.x; a45.y = x1.y;
          f32x2 a67; a67.x = x1.z; a67.y = x1.w;
          uint4 ou, ov;
          ou.x = packpair(a01 * b01);
          ou.y = packpair(a23 * b23);
          ou.z = packpair(a45 * b45);
          ou.w = packpair(a67 * b67);
          f32x2 d0v = a01 - b01, d1v = a23 - b23;
          f32x2 d2v = a45 - b45, d3v = a67 - b67;
          ov.x = packpair(__builtin_elementwise_max(d0v, -d0v));
          ov.y = packpair(__builtin_elementwise_max(d1v, -d1v));
          ov.z = packpair(__builtin_elementwise_max(d2v, -d2v));
          ov.w = packpair(__builtin_elementwise_max(d3v, -d3v));
          afu[rb] = __builtin_bit_cast(bf16x8, ou);
          afv[ks][rb] = __builtin_bit_cast(bf16x8, ov);
        }
        const int kg = ks * 2 + q;
        bf16x8 bfr[4];
#pragma unroll
        for (int cb = 0; cb < 4; cb++) {
          int ch = wcl * 128 + cb * 32 + n;
          bfr[cb] = *(const bf16x8*)(B2 + ch * 64 + ((kg ^ ((ch >> 1) & 3)) * 16));
        }
#pragma unroll
        for (int rb = 0; rb < 2; rb++)
#pragma unroll
          for (int cb = 0; cb < 4; cb++)
            acc[rb][cb] = __builtin_amdgcn_mfma_f32_32x32x16_bf16(
                afu[rb], bfr[cb], acc[rb][cb], 0, 0, 0);
      }
    }
    // ---- v-phase: B tile lk=2m+1 in buf1; pure bfr->MFMA burst ----
    asm volatile("s_waitcnt vmcnt(0)\n\ts_barrier" ::: "memory");
    if (m < 15) prefetch_B(2 * m + 2, 0);
    {
      const char* B2 = smem + BB_OFF + 16384;
#pragma unroll
      for (int ks = 0; ks < 2; ks++) {
        const int kg = ks * 2 + q;
        bf16x8 bfr[4];
#pragma unroll
        for (int cb = 0; cb < 4; cb++) {
          int ch = wcl * 128 + cb * 32 + n;
          bfr[cb] = *(const bf16x8*)(B2 + ch * 64 + ((kg ^ ((ch >> 1) & 3)) * 16));
        }
#pragma unroll
        for (int rb = 0; rb < 2; rb++)
#pragma unroll
          for (int cb = 0; cb < 4; cb++)
            acc[rb][cb] = __builtin_amdgcn_mfma_f32_32x32x16_bf16(
                afv[ks][rb], bfr[cb], acc[rb][cb], 0, 0, 0);
      }
    }
  }

  // ---- epilogue: emit fwd (i,j) and transposed (j,i) partial scores ----
  __syncthreads();  // all waves done with both B buffers
  {
    float b1v = b1[ch0 + tid];
    for (int j = 0; j < 16; j++) {
      int grow = (bb * 256 + bj0 + j) * 512 + ch0 + tid;
      *(float*)(smem + CJB_OFF + (j * 256 + tid) * 4) = Cw[grow] + b1v;
      *(float*)(smem + AJB_OFF + (j * 256 + tid) * 4) = Aw[grow] + b1v;
    }
    *(float*)(smem + W2S_OFF + tid * 4) = w2[ch0 + tid];
  }
  __syncthreads();

  float* RED = (float*)(smem + RED_OFF);
  float* RED2 = (float*)(smem + RED2_OFF);
  const float* CJB = (const float*)(smem + CJB_OFF);
  const float* AJB = (const float*)(smem + AJB_OFF);
  const float* W2S = (const float*)(smem + W2S_OFF);
  for (int rb = 0; rb < 2; rb++) {
    float av[4][2], civ[4][2], w2v[4];
    int chls[4];
    for (int cb = 0; cb < 4; cb++) {
      int chl = wcl * 128 + cb * 32 + n;
      chls[cb] = chl;
      w2v[cb] = W2S[chl];
      int irow = (bb * 256 + bi0 + wr * 4 + rb * 2) * 512 + ch0 + chl;
      av[cb][0] = Aw[irow];
      av[cb][1] = Aw[irow + 512];
      civ[cb][0] = Cw[irow];
      civ[cb][1] = Cw[irow + 512];
    }
    for (int r = 0; r < 16; r++) {
      int rowl = (r & 3) + 8 * (r >> 2) + 4 * q;  // C/D layout (m74/m101)
      int j = rowl & 15;
      int hi = r >> 3;
      float vf = 0.f, vt = 0.f;
      for (int cb = 0; cb < 4; cb++) {
        float base = acc[rb][cb][r];
        float hf = base + av[cb][hi] + CJB[j * 256 + chls[cb]];
        if (hf > 0.f) vf += hf * w2v[cb];
        float ht = base + civ[cb][hi] + AJB[j * 256 + chls[cb]];
        if (ht > 0.f) vt += ht * w2v[cb];
      }
      vf += __shfl_xor(vf, 1); vt += __shfl_xor(vt, 1);
      vf += __shfl_xor(vf, 2); vt += __shfl_xor(vt, 2);
      vf += __shfl_xor(vf, 4); vt += __shfl_xor(vt, 4);
      if ((n & 7) == 0) {
        int p = wr * 64 + rb * 32 + rowl;
        int slot = p * 9 + wcl * 4 + (n >> 3);
        RED[slot] = vf;
        RED2[slot] = vt;
      }
    }
  }

  __syncthreads();
  {
    int p = tid & 127;
    int gi = bi0 + (p >> 4), gj = bj0 + (p & 15);
    float half_b2 = 0.5f * b2[0];  // each ch-half block contributes half of b2
    if (tid < 128) {
      float s = half_b2;
      for (int u = 0; u < 8; u++) s += RED[p * 9 + u];
      if (gi <= gj) atomicAdd(out + (bb * 256 + gi) * 256 + gj, s);
    } else {
      float s = half_b2;
      for (int u = 0; u < 8; u++) s += RED2[p * 9 + u];
      if (gi < gj) atomicAdd(out + (bb * 256 + gj) * 256 + gi, s);
    }
  }
}

// ---------------- launcher ----------------
extern "C" void kernel_launch(void* const* d_in, const int* in_sizes, int n_in,
                              void* d_out, int out_size, void* d_ws, size_t ws_size,
                              hipStream_t stream) {
  const float* E = (const float*)d_in[0];
  const float* W1 = (const float*)d_in[1];
  const float* b1 = (const float*)d_in[2];
  const float* W2 = (const float*)d_in[3];
  const float* b2 = (const float*)d_in[4];
  float* out = (float*)d_out;
  char* ws = (char*)d_ws;
  u16* E16 = (u16*)(ws + WS_E16);
  u16* WT = (u16*)(ws + WS_WT);
  float* Aw = (float*)(ws + WS_A);
  float* Cw = (float*)(ws + WS_C);

  // out accumulated via atomicAdd from the two channel-half blocks: zero first
  hipMemsetAsync(out, 0, (size_t)out_size * sizeof(float), stream);
  hipLaunchKernelGGL(k_cvt, dim3(768), dim3(256), 0, stream, E, E16, W1, WT);
  hipLaunchKernelGGL(k_ac, dim3(8, 8), dim3(256), 0, stream, E16, WT, Aw, Cw);
  // 272 = # of 8x16 pair-tiles intersecting the upper triangle (tj*(tj+1)+ti)
  hipLaunchKernelGGL(k_pair, dim3(272, 2, 4), dim3(256), 0, stream,
                     E, E16, WT, Aw, Cw, b1, W2, b2, out);
}

// Round 9
// 265.674 us; speedup vs baseline: 3.0661x; 1.0527x over previous
//
#include <hip/hip_runtime.h>
#include <stdint.h>

typedef unsigned int u32;
typedef unsigned short u16;
typedef __attribute__((ext_vector_type(8))) _Float16 f16x8;
typedef __attribute__((ext_vector_type(16))) float f32x16;

#define DEVI __device__ __forceinline__

// ---------------- numeric helpers ----------------
DEVI u16 f2h(float f) {  // f32 -> f16 RNE (v_cvt_f16_f32)
  _Float16 h = (_Float16)f;
  return __builtin_bit_cast(u16, h);
}

// ---------------- ws layout (bytes) ----------------
#define WS_E16 0             // f16 E, [1024 rows][512]
#define WS_WT (1u << 20)     // f16 W1^T, [512 ch][2048 k]
#define WS_A (3u << 20)      // f32 a = E@Wa
#define WS_C (5u << 20)      // f32 c = E@Wb

// ---------------- kernel 0: fused E->f16 (blocks 0..511) and
//                  W1 (2048x512 f32) -> W16T (512x2048 f16) (blocks 512..767)
__global__ void k_cvt(const float* __restrict__ E, u16* __restrict__ E16,
                      const float* __restrict__ W1, u16* __restrict__ WT) {
  __shared__ float tile[64][65];
  if (blockIdx.x < 512) {
    int i = (blockIdx.x * blockDim.x + threadIdx.x) * 4;
    float4 v = *(const float4*)(E + i);
    ushort4 o;
    o.x = f2h(v.x); o.y = f2h(v.y); o.z = f2h(v.z); o.w = f2h(v.w);
    *(ushort4*)(E16 + i) = o;
    return;
  }
  int bid = blockIdx.x - 512;
  int t = threadIdx.x;
  int kBase = (bid & 31) * 64;   // 32 k-tiles
  int chBase = (bid >> 5) * 64;  // 8 ch-tiles
  int lr = t >> 4, lc = (t & 15) * 4;
  for (int rr = 0; rr < 4; rr++) {
    int kr = lr + rr * 16;
    float4 v = *(const float4*)(W1 + (kBase + kr) * 512 + chBase + lc);
    tile[kr][lc] = v.x; tile[kr][lc + 1] = v.y;
    tile[kr][lc + 2] = v.z; tile[kr][lc + 3] = v.w;
  }
  __syncthreads();
  int ch = t >> 2, ks = (t & 3) * 16;
  u32 w[8];
  for (int u = 0; u < 8; u++) {
    u16 lo = f2h(tile[ks + 2 * u][ch]);
    u16 hi = f2h(tile[ks + 2 * u + 1][ch]);
    w[u] = (u32)lo | ((u32)hi << 16);
  }
  u16* dst = WT + (chBase + ch) * 2048 + kBase + ks;
  uint4 s0; s0.x = w[0]; s0.y = w[1]; s0.z = w[2]; s0.w = w[3];
  uint4 s1; s1.x = w[4]; s1.y = w[5]; s1.z = w[6]; s1.w = w[7];
  *(uint4*)(dst) = s0;
  *(uint4*)(dst + 8) = s1;
}

// ---------------- kernel 1: a = E@Wa, c = E@Wb (f16 MFMA) ----------------
__global__ __launch_bounds__(256, 4) void k_ac(const u16* __restrict__ E16,
                                               const u16* __restrict__ WT,
                                               float* __restrict__ Aw,
                                               float* __restrict__ Cw) {
  __shared__ __align__(16) char smem[16384];
  char* sA = smem;
  char* sB = smem + 8192;
  const int tid = threadIdx.x;
  const int lane = tid & 63, wid = tid >> 6;
  const int wr = wid >> 1, wcl = wid & 1;
  const int n = lane & 31, q = lane >> 5;
  const int rowBase = blockIdx.y * 128;
  const int chBase = blockIdx.x * 128;
  const int halfOff = (chBase >= 512) ? 512 : 0;
  const int chSrc0 = chBase - halfOff;
  f32x16 acc[2][2];
  for (int a = 0; a < 2; a++)
    for (int c = 0; c < 2; c++)
      for (int e = 0; e < 16; e++) acc[a][c][e] = 0.f;
  for (int kc = 0; kc < 16; kc++) {
    const int k0 = kc * 32;
    __syncthreads();
    for (int s2 = 0; s2 < 2; s2++) {
      int s = tid * 2 + s2;
      int row = s >> 2, pg = s & 3, lg = pg ^ ((row >> 1) & 3);
      *(uint4*)(sA + row * 64 + lg * 16) =
          *(const uint4*)(E16 + (rowBase + row) * 512 + k0 + pg * 8);
      *(uint4*)(sB + row * 64 + lg * 16) =
          *(const uint4*)(WT + (chSrc0 + row) * 2048 + halfOff + k0 + pg * 8);
    }
    __syncthreads();
    for (int ks = 0; ks < 2; ks++) {
      int kg = ks * 2 + q;
      f16x8 af[2], bfr[2];
      for (int rb = 0; rb < 2; rb++) {
        int row = wr * 64 + rb * 32 + n;
        af[rb] = *(const f16x8*)(sA + row * 64 + ((kg ^ ((row >> 1) & 3)) * 16));
      }
      for (int cb = 0; cb < 2; cb++) {
        int ch = wcl * 64 + cb * 32 + n;
        bfr[cb] = *(const f16x8*)(sB + ch * 64 + ((kg ^ ((ch >> 1) & 3)) * 16));
      }
      for (int rb = 0; rb < 2; rb++)
        for (int cb = 0; cb < 2; cb++)
          acc[rb][cb] = __builtin_amdgcn_mfma_f32_32x32x16_f16(af[rb], bfr[cb],
                                                              acc[rb][cb], 0, 0, 0);
    }
  }
  for (int rb = 0; rb < 2; rb++)
    for (int cb = 0; cb < 2; cb++)
      for (int r = 0; r < 16; r++) {
        int rowl = (r & 3) + 8 * (r >> 2) + 4 * q;
        int rowg = rowBase + wr * 64 + rb * 32 + rowl;
        int chg = chBase + wcl * 64 + cb * 32 + n;
        float v = acc[rb][cb][r];
        if (chg < 512) Aw[rowg * 512 + chg] = v;
        else Cw[rowg * 512 + chg - 512] = v;
      }
}

// ---------------- kernel 2: pair kernel (f16, symmetric, interleaved u/v) ---
// P(i,j) symmetric -> triangular tiles (272 of 512), dual epilogue, atomic
// combine of the two channel-half blocks (blockIdx.y) into zeroed out.
// Formation in PACKED f16 (v_pk_mul/sub/max_f16 on f16x8): no unpack/repack.
// lk even = u-chunk d=(lk>>1)*32 (ei*ej), lk odd = v-chunk same d (|ei-ej|);
// one e-read forms both; v-frags held in regs one phase. One raw
// s_barrier+vmcnt(0) per phase, depth-1 async global_load_lds prefetch.
#define EI_OFF 0             // 8 rows x 520 f16 (1040B) = 8320
#define EJ_OFF 8320          // 16 rows x 1040B = 16640 -> 24960
#define BB_OFF 24960         // 2 x 16384 -> 57728
#define AJB_OFF 24960        // epilogue alias over B buf0 (16*256*4 = 16KB)
#define CJB_OFF 41344        // epilogue alias over B buf1 (16KB)
#define W2S_OFF 57728        // 1024 -> 58752
#define RED_OFF 58752        // 128*9*4 = 4608 -> 63360
#define RED2_OFF 63360       // 4608 -> 67968
#define SMEM2 67968

// acc[2][4]=128 AGPR + ~120 arch VGPR <= 256: 2 waves/SIMD structural max.
__global__ __launch_bounds__(256, 2) void k_pair(
    const u16* __restrict__ E16, const u16* __restrict__ WT,
    const float* __restrict__ Aw, const float* __restrict__ Cw,
    const float* __restrict__ b1, const float* __restrict__ w2,
    const float* __restrict__ b2, float* __restrict__ out) {
  __shared__ __align__(16) char smem[SMEM2];
  const int tid = threadIdx.x;
  const int lane = tid & 63, wid = tid >> 6;
  const int wr = wid >> 1, wcl = wid & 1;
  const int n = lane & 31, q = lane >> 5;
  const int bb = blockIdx.z;
  const int ch0 = blockIdx.y * 256;

  // invert triangular tile index: f = tj*(tj+1) + ti, ti in [0, 2*tj+2)
  int f = blockIdx.x;
  int tj = (int)((__builtin_sqrtf(4.0f * (float)f + 1.0f) - 1.0f) * 0.5f);
  while ((tj + 1) * (tj + 2) <= f) tj++;
  while (tj * (tj + 1) > f) tj--;
  const int ti = f - tj * (tj + 1);
  const int bi0 = ti * 8;
  const int bj0 = tj * 16;

  // async-stage B tile lk: [256 ch][32 k], k-col = 1024 + (lk>>1)*32 + (lk&1)*512
  auto prefetch_B = [&](int lk, int nbuf) {
    const int col0 = 1024 + ((lk >> 1) << 5) + ((lk & 1) << 9);
    char* base = smem + BB_OFF + nbuf * 16384 + wid * 4096;
    for (int t = 0; t < 4; t++) {
      int seg = wid * 4 + t;
      int row = seg * 16 + (lane >> 2);
      int pg = (lane & 3) ^ ((row >> 1) & 3);
      const u16* g = WT + (ch0 + row) * 2048 + col0 + pg * 8;
      __builtin_amdgcn_global_load_lds(
          (const __attribute__((address_space(1))) void*)g,
          (__attribute__((address_space(3))) void*)(base + t * 1024), 16, 0, 0);
    }
  };

  prefetch_B(0, 0);

  // stage e-tiles f16 (rows 0..7 = e_i, 8..23 = e_j), both 520-elem stride
  for (int s = tid; s < 1536; s += 256) {
    int row = s >> 6, c16 = s & 63;
    int grow = (row < 8) ? (bi0 + row) : (bj0 + row - 8);
    const u16* src = E16 + (bb * 256 + grow) * 512 + c16 * 8;
    int off = (row < 8) ? (EI_OFF + (row * 520 + c16 * 8) * 2)
                        : (EJ_OFF + ((row - 8) * 520 + c16 * 8) * 2);
    *(uint4*)(smem + off) = *(const uint4*)src;
  }
  __syncthreads();  // e-tiles visible; also drains first prefetch

  const u16* eip = (const u16*)(smem + EI_OFF) + (wr * 4 + (n >> 4)) * 520;
  const u16* ejp = (const u16*)(smem + EJ_OFF) + (n & 15) * 520;

  f32x16 acc[2][4];
  for (int a = 0; a < 2; a++)
    for (int c = 0; c < 4; c++)
      for (int e = 0; e < 16; e++) acc[a][c][e] = 0.f;

  f16x8 afv[2][2];  // held v-fragments [ks][rb]
  for (int m = 0; m < 16; m++) {
    const int dBase = m * 32;
    // ---- u-phase: B tile lk=2m in buf0 ----
    asm volatile("s_waitcnt vmcnt(0)\n\ts_barrier" ::: "memory");
    prefetch_B(2 * m + 1, 1);
    {
      const char* B2 = smem + BB_OFF;
#pragma unroll
      for (int ks = 0; ks < 2; ks++) {
        const int d0 = dBase + ks * 16 + q * 8;
        f16x8 eb = *(const f16x8*)(ejp + d0);
        f16x8 afu[2];
#pragma unroll
        for (int rb = 0; rb < 2; rb++) {
          f16x8 ea = *(const f16x8*)(eip + rb * 1040 + d0);  // 2 rows x 520
          f16x8 u = ea * eb;                                  // v_pk_mul_f16
          f16x8 dd = ea - eb;                                 // v_pk_add/sub
          f16x8 vv = __builtin_elementwise_max(dd, -dd);      // v_pk_max_f16
          afu[rb] = u;
          afv[ks][rb] = vv;
        }
        const int kg = ks * 2 + q;
        f16x8 bfr[4];
#pragma unroll
        for (int cb = 0; cb < 4; cb++) {
          int ch = wcl * 128 + cb * 32 + n;
          bfr[cb] = *(const f16x8*)(B2 + ch * 64 + ((kg ^ ((ch >> 1) & 3)) * 16));
        }
#pragma unroll
        for (int rb = 0; rb < 2; rb++)
#pragma unroll
          for (int cb = 0; cb < 4; cb++)
            acc[rb][cb] = __builtin_amdgcn_mfma_f32_32x32x16_f16(
                afu[rb], bfr[cb], acc[rb][cb], 0, 0, 0);
      }
    }
    // ---- v-phase: B tile lk=2m+1 in buf1; pure bfr->MFMA burst ----
    asm volatile("s_waitcnt vmcnt(0)\n\ts_barrier" ::: "memory");
    if (m < 15) prefetch_B(2 * m + 2, 0);
    {
      const char* B2 = smem + BB_OFF + 16384;
#pragma unroll
      for (int ks = 0; ks < 2; ks++) {
        const int kg = ks * 2 + q;
        f16x8 bfr[4];
#pragma unroll
        for (int cb = 0; cb < 4; cb++) {
          int ch = wcl * 128 + cb * 32 + n;
          bfr[cb] = *(const f16x8*)(B2 + ch * 64 + ((kg ^ ((ch >> 1) & 3)) * 16));
        }
#pragma unroll
        for (int rb = 0; rb < 2; rb++)
#pragma unroll
          for (int cb = 0; cb < 4; cb++)
            acc[rb][cb] = __builtin_amdgcn_mfma_f32_32x32x16_f16(
                afv[ks][rb], bfr[cb], acc[rb][cb], 0, 0, 0);
      }
    }
  }

  // ---- epilogue: emit fwd (i,j) and transposed (j,i) partial scores ----
  __syncthreads();  // all waves done with both B buffers
  {
    float b1v = b1[ch0 + tid];
    for (int j = 0; j < 16; j++) {
      int grow = (bb * 256 + bj0 + j) * 512 + ch0 + tid;
      *(float*)(smem + CJB_OFF + (j * 256 + tid) * 4) = Cw[grow] + b1v;
      *(float*)(smem + AJB_OFF + (j * 256 + tid) * 4) = Aw[grow] + b1v;
    }
    *(float*)(smem + W2S_OFF + tid * 4) = w2[ch0 + tid];
  }
  __syncthreads();

  float* RED = (float*)(smem + RED_OFF);
  float* RED2 = (float*)(smem + RED2_OFF);
  const float* CJB = (const float*)(smem + CJB_OFF);
  const float* AJB = (const float*)(smem + AJB_OFF);
  const float* W2S = (const float*)(smem + W2S_OFF);
  for (int rb = 0; rb < 2; rb++) {
    float av[4][2], civ[4][2], w2v[4];
    int chls[4];
    for (int cb = 0; cb < 4; cb++) {
      int chl = wcl * 128 + cb * 32 + n;
      chls[cb] = chl;
      w2v[cb] = W2S[chl];
      int irow = (bb * 256 + bi0 + wr * 4 + rb * 2) * 512 + ch0 + chl;
      av[cb][0] = Aw[irow];
      av[cb][1] = Aw[irow + 512];
      civ[cb][0] = Cw[irow];
      civ[cb][1] = Cw[irow + 512];
    }
    for (int r = 0; r < 16; r++) {
      int rowl = (r & 3) + 8 * (r >> 2) + 4 * q;  // C/D layout (m74/m101)
      int j = rowl & 15;
      int hi = r >> 3;
      float vf = 0.f, vt = 0.f;
      for (int cb = 0; cb < 4; cb++) {
        float base = acc[rb][cb][r];
        float hf = base + av[cb][hi] + CJB[j * 256 + chls[cb]];
        if (hf > 0.f) vf += hf * w2v[cb];
        float ht = base + civ[cb][hi] + AJB[j * 256 + chls[cb]];
        if (ht > 0.f) vt += ht * w2v[cb];
      }
      vf += __shfl_xor(vf, 1); vt += __shfl_xor(vt, 1);
      vf += __shfl_xor(vf, 2); vt += __shfl_xor(vt, 2);
      vf += __shfl_xor(vf, 4); vt += __shfl_xor(vt, 4);
      if ((n & 7) == 0) {
        int p = wr * 64 + rb * 32 + rowl;
        int slot = p * 9 + wcl * 4 + (n >> 3);
        RED[slot] = vf;
        RED2[slot] = vt;
      }
    }
  }

  __syncthreads();
  {
    int p = tid & 127;
    int gi = bi0 + (p >> 4), gj = bj0 + (p & 15);
    float half_b2 = 0.5f * b2[0];  // each ch-half block contributes half of b2
    if (tid < 128) {
      float s = half_b2;
      for (int u = 0; u < 8; u++) s += RED[p * 9 + u];
      if (gi <= gj) atomicAdd(out + (bb * 256 + gi) * 256 + gj, s);
    } else {
      float s = half_b2;
      for (int u = 0; u < 8; u++) s += RED2[p * 9 + u];
      if (gi < gj) atomicAdd(out + (bb * 256 + gj) * 256 + gi, s);
    }
  }
}

// ---------------- launcher ----------------
extern "C" void kernel_launch(void* const* d_in, const int* in_sizes, int n_in,
                              void* d_out, int out_size, void* d_ws, size_t ws_size,
                              hipStream_t stream) {
  const float* E = (const float*)d_in[0];
  const float* W1 = (const float*)d_in[1];
  const float* b1 = (const float*)d_in[2];
  const float* W2 = (const float*)d_in[3];
  const float* b2 = (const float*)d_in[4];
  float* out = (float*)d_out;
  char* ws = (char*)d_ws;
  u16* E16 = (u16*)(ws + WS_E16);
  u16* WT = (u16*)(ws + WS_WT);
  float* Aw = (float*)(ws + WS_A);
  float* Cw = (float*)(ws + WS_C);

  // out accumulated via atomicAdd from the two channel-half blocks: zero first
  hipMemsetAsync(out, 0, (size_t)out_size * sizeof(float), stream);
  hipLaunchKernelGGL(k_cvt, dim3(768), dim3(256), 0, stream, E, E16, W1, WT);
  hipLaunchKernelGGL(k_ac, dim3(8, 8), dim3(256), 0, stream, E16, WT, Aw, Cw);
  // 272 = # of 8x16 pair-tiles intersecting the upper triangle (tj*(tj+1)+ti)
  hipLaunchKernelGGL(k_pair, dim3(272, 2, 4), dim3(256), 0, stream,
                     E16, WT, Aw, Cw, b1, W2, b2, out);
}